// Round 4
// baseline (130.280 us; speedup 1.0000x reference)
//
#include <hip/hip_runtime.h>
#include <math.h>

typedef unsigned short ushort;
typedef unsigned int uint;
typedef __attribute__((ext_vector_type(8))) short bf16x8;
typedef __attribute__((ext_vector_type(4))) float f32x4;
typedef __attribute__((ext_vector_type(16))) float f32x16;
typedef __attribute__((ext_vector_type(2))) unsigned uint2v;

constexpr int Bc  = 16;
constexpr float EPSc = 1e-5f;
constexpr float QSC  = 0.18033688f;  // 0.125 * log2(e): softmax exp -> exp2

// v_cvt_pk_bf16_f32: one instr per bf16 pair (no builtin on gfx950)
__device__ __forceinline__ uint cvt2(float a, float b) {
    uint r;
    asm("v_cvt_pk_bf16_f32 %0, %1, %2" : "=v"(r) : "v"(a), "v"(b));
    return r;
}
__device__ __forceinline__ ushort f2bf_fast(float f) {
    uint r;
    asm("v_cvt_pk_bf16_f32 %0, %1, %2" : "=v"(r) : "v"(f), "v"(f));
    return (ushort)r;
}
// permlane32_swap: r.x = [a.lanes0-31 | b.lanes0-31], r.y = [a.lanes32-63 | b.lanes32-63]
__device__ __forceinline__ uint2v plswap(uint a, uint b) {
#if __has_builtin(__builtin_amdgcn_permlane32_swap)
    return __builtin_amdgcn_permlane32_swap(a, b, false, false);
#else
    asm volatile("v_permlane32_swap_b32 %0, %1" : "+v"(a), "+v"(b));
    uint2v r; r.x = a; r.y = b; return r;
#endif
}
#if __has_builtin(__builtin_amdgcn_exp2f)
#define EXP2F(x) __builtin_amdgcn_exp2f(x)
#else
#define EXP2F(x) __expf((x) * 0.69314718f)
#endif
__device__ __forceinline__ void gl_lds16(const ushort* g, ushort* l) {
    __builtin_amdgcn_global_load_lds(
        (const __attribute__((address_space(1))) void*)g,
        (__attribute__((address_space(3))) void*)l, 16, 0, 0);
}

// ---------------------------------------------------------------------------
// K1: fused GroupNorm, ONE-PASS: stage the 128KB (b,g) slice in LDS f32
// while accumulating stats; normalize straight out of LDS (no global
// re-read). Blocks 0..127: slices. Blocks 128..191: weight cvt.
// ---------------------------------------------------------------------------
__global__ __launch_bounds__(1024, 4) void norm_k(
    const float* __restrict__ x, const float* __restrict__ nw,
    const float* __restrict__ nb, const float* __restrict__ qkvw,
    const float* __restrict__ pw, ushort* __restrict__ xt,
    ushort* __restrict__ wqb, ushort* __restrict__ pwb) {
    __shared__ float XS[32768];   // 128KB: [c 32][n 1024]
    __shared__ float rs[16], rq[16], bc[2];
    int blk = blockIdx.x;
    int t = threadIdx.x;
    if (blk < 128) {
        int b = blk >> 3, g = blk & 7;
        const float* xs = x + ((size_t)(b * 8 + g)) * 32768;
        const float4* p4 = (const float4*)xs;
        float s = 0.f, s2 = 0.f;
#pragma unroll
        for (int i = 0; i < 8; ++i) {
            float4 v = p4[t + i * 1024];
            s += (v.x + v.y) + (v.z + v.w);
            s2 += (v.x * v.x + v.y * v.y) + (v.z * v.z + v.w * v.w);
            *(float4*)&XS[(t + i * 1024) * 4] = v;
        }
#pragma unroll
        for (int off = 1; off < 64; off <<= 1) {
            s += __shfl_xor(s, off);
            s2 += __shfl_xor(s2, off);
        }
        int wv = t >> 6, lane = t & 63;
        if (lane == 0) { rs[wv] = s; rq[wv] = s2; }
        __syncthreads();
        if (t == 0) {
            float ts = 0.f, tq = 0.f;
#pragma unroll
            for (int i = 0; i < 16; ++i) { ts += rs[i]; tq += rq[i]; }
            float mean = ts * (1.f / 32768.f);
            float var  = tq * (1.f / 32768.f) - mean * mean;
            bc[0] = mean; bc[1] = rsqrtf(var + EPSc);
        }
        __syncthreads();
        float mean = bc[0], inv = bc[1];
        int n = t;
        uint w[16];
#pragma unroll
        for (int c = 0; c < 32; c += 2) {
            float w0 = inv * nw[g * 32 + c];
            float b0 = nb[g * 32 + c] - mean * w0;
            float w1 = inv * nw[g * 32 + c + 1];
            float b1 = nb[g * 32 + c + 1] - mean * w1;
            float v0 = XS[c * 1024 + n] * w0 + b0;
            float v1 = XS[(c + 1) * 1024 + n] * w1 + b1;
            w[c >> 1] = cvt2(v0, v1);
        }
        ushort* dst = &xt[((size_t)(b * 1024 + n)) * 256 + g * 32];
#pragma unroll
        for (int i = 0; i < 4; ++i) {
            uint4 u; u.x = w[i*4]; u.y = w[i*4+1]; u.z = w[i*4+2]; u.w = w[i*4+3];
            *(uint4*)&dst[i * 8] = u;
        }
    } else {
        int idx = ((blk - 128) * 1024 + t) * 4;
        if (idx < 196608) {
            int row = idx >> 8;
            float sc = (row < 256) ? QSC : 1.f;
            float4 v = *(const float4*)&qkvw[idx];
            uint2 u; u.x = cvt2(v.x * sc, v.y * sc); u.y = cvt2(v.z * sc, v.w * sc);
            *(uint2*)&wqb[idx] = u;
        } else {
            int j = idx - 196608;
            float4 v = *(const float4*)&pw[j];
            uint2 u; u.x = cvt2(v.x, v.y); u.y = cvt2(v.z, v.w);
            *(uint2*)&pwb[j] = u;
        }
    }
}

// ---------------------------------------------------------------------------
// K3: qkv GEMM (unchanged, proven): BK=64 async dbuf, 1 barrier/iter.
// 128x128 tile, 4 waves. cy 0..3 -> qkT transposed; cy 4..5 -> vbuf natural.
// ---------------------------------------------------------------------------
__global__ __launch_bounds__(256, 2) void qkv_gemm_k(
    const ushort* __restrict__ wq, const ushort* __restrict__ xt,
    const float* __restrict__ wb, ushort* __restrict__ qkT,
    ushort* __restrict__ vbuf) {
    int b = blockIdx.z, cy = blockIdx.y, sx = blockIdx.x;
    __shared__ ushort SB[2][2][128 * 64];
    int t = threadIdx.x, lane = t & 63, w = t >> 6;
    int quad = lane >> 4, l15 = lane & 15;
    int wm = w >> 1, wn = w & 1;
    const ushort* wrow = wq + (size_t)cy * 128 * 256;
    const ushort* xrow = xt + ((size_t)b * 1024 + sx * 128) * 256;
    bool tpath = (cy < 4);
    int r0 = t >> 3;
    int cs = (t & 7) ^ (r0 & 7);
    int dst = t * 8;
#pragma unroll
    for (int ps = 0; ps < 4; ++ps) {
        int r = r0 + ps * 32;
        gl_lds16(&wrow[(size_t)r * 256 + cs * 8], &SB[0][0][ps * 2048 + dst]);
        gl_lds16(&xrow[(size_t)r * 256 + cs * 8], &SB[0][1][ps * 2048 + dst]);
    }
    __syncthreads();
    int s0 = quad ^ (l15 & 7);
    f32x4 acc[4][4] = {};
    int cur = 0;
    for (int ki = 0; ki < 4; ++ki) {
        if (ki < 3) {
            int k0 = (ki + 1) * 64, nx = cur ^ 1;
#pragma unroll
            for (int ps = 0; ps < 4; ++ps) {
                int r = r0 + ps * 32;
                gl_lds16(&wrow[(size_t)r * 256 + k0 + cs * 8], &SB[nx][0][ps * 2048 + dst]);
                gl_lds16(&xrow[(size_t)r * 256 + k0 + cs * 8], &SB[nx][1][ps * 2048 + dst]);
            }
        }
        const ushort* Wc = SB[cur][0];
        const ushort* Xc = SB[cur][1];
        const ushort* Am = tpath ? Xc : Wc;
        const ushort* Bn = tpath ? Wc : Xc;
#pragma unroll
        for (int kk = 0; kk < 2; ++kk) {
            int sl = s0 ^ (kk * 4);
            bf16x8 fa[4], fb[4];
#pragma unroll
            for (int mi = 0; mi < 4; ++mi)
                fa[mi] = *(const bf16x8*)&Am[(wm * 64 + mi * 16 + l15) * 64 + sl * 8];
#pragma unroll
            for (int ni = 0; ni < 4; ++ni)
                fb[ni] = *(const bf16x8*)&Bn[(wn * 64 + ni * 16 + l15) * 64 + sl * 8];
#pragma unroll
            for (int mi = 0; mi < 4; ++mi)
#pragma unroll
                for (int ni = 0; ni < 4; ++ni)
                    acc[mi][ni] = __builtin_amdgcn_mfma_f32_16x16x32_bf16(
                        fa[mi], fb[ni], acc[mi][ni], 0, 0, 0);
        }
        __syncthreads();
        cur ^= 1;
    }
    __syncthreads();
    ushort* Tw = ((ushort*)SB) + w * (64 * 72);
    float bsc = (tpath && cy < 2) ? QSC : 1.f;
    if (tpath) {
#pragma unroll
        for (int ni = 0; ni < 4; ++ni) {
            float bias = wb[cy * 128 + wn * 64 + ni * 16 + l15] * bsc;
#pragma unroll
            for (int mi = 0; mi < 4; ++mi)
#pragma unroll
                for (int rr = 0; rr < 4; ++rr)
                    Tw[(mi * 16 + quad * 4 + rr) * 72 + ni * 16 + l15] =
                        f2bf_fast(acc[mi][ni][rr] + bias);
        }
    } else {
#pragma unroll
        for (int mi = 0; mi < 4; ++mi)
#pragma unroll
            for (int rr = 0; rr < 4; ++rr) {
                float bias = wb[cy * 128 + wm * 64 + mi * 16 + quad * 4 + rr];
#pragma unroll
                for (int ni = 0; ni < 4; ++ni)
                    Tw[(mi * 16 + quad * 4 + rr) * 72 + ni * 16 + l15] =
                        f2bf_fast(acc[mi][ni][rr] + bias);
            }
    }
    __asm__ __volatile__("" ::: "memory");
    int row8 = lane >> 3, ch = lane & 7;
#pragma unroll
    for (int p = 0; p < 8; ++p) {
        int row = p * 8 + row8;
        uint4 u = *(const uint4*)&Tw[row * 72 + ch * 8];
        if (tpath) {
            int sp = sx * 128 + wm * 64 + row;
            *(uint4*)&qkT[((size_t)b * 1024 + sp) * 512 + cy * 128 + wn * 64 + ch * 8] = u;
        } else {
            int chanloc = (cy - 4) * 128 + wm * 64 + row;
            *(uint4*)&vbuf[((size_t)b * 256 + chanloc) * 1024 + sx * 128 + wn * 64 + ch * 8] = u;
        }
    }
}

// ---------------------------------------------------------------------------
// K4: flash attention, 32x32 MFMA, in-register softmax, round-4: 8-wave
// blocks (512 thr) with j-SPLIT: wave (iw 0..3, jw 0..1) computes i-cols
// iw*32..+32 and j-half jw of each 64-j tile -> 2 blocks/CU x 8 waves =
// 16 waves/CU (4/SIMD), double round-3 TLP at identical chip-wide work.
// Cross-jw O/lsum reduce via LDS at the end. K/V staging unchanged (32KB).
// ---------------------------------------------------------------------------
__global__ __launch_bounds__(512, 4) void attn_k(
    const ushort* __restrict__ qkT, const ushort* __restrict__ vbuf,
    ushort* __restrict__ ot) {
    int bh = blockIdx.x;
    int i0 = blockIdx.y * 128;
    int b = bh >> 2, h = bh & 3;
    const ushort* qTb = qkT + (size_t)b * 1024 * 512 + h * 64;
    const ushort* kTb = qTb + 256;
    const ushort* vb  = vbuf + ((size_t)(b * 256 + h * 64)) * 1024;
    __shared__ ushort SM[16384];          // Ks[2][4096] | Vs[2][4096] (32KB)
    __shared__ float LS[4][32];           // jw=1 lsum exchange
    ushort* Ks0 = SM;
    ushort* Vs0 = SM + 8192;
    int t = threadIdx.x, lane = t & 63, wv = t >> 6;   // 8 waves
    int iw = wv & 3, jw = wv >> 2;
    int l31 = lane & 31, hf = lane >> 5;
    int srow = t >> 3, pc = t & 7;        // staging: 512 thr = 64 rows x 8 chunks
    {
        int c = pc ^ (srow & 7);
        gl_lds16(&kTb[(size_t)srow * 512 + c * 8], &Ks0[t * 8]);
        gl_lds16(&vb[(size_t)srow * 1024 + c * 8], &Vs0[t * 8]);
    }
    // Q frags direct from global: B-frag col=i=l31, k = ks*16 + hf*8 + e
    bf16x8 qf[4];
#pragma unroll
    for (int ks = 0; ks < 4; ++ks)
        qf[ks] = *(const bf16x8*)
            &qTb[(size_t)(i0 + iw * 32 + l31) * 512 + ks * 16 + hf * 8];
    __syncthreads();
    f32x16 oT0 = {}, oT1 = {};   // O^T[d][i], d-halves (j-partial: this jw)
    float lsum = 0.f;
    int cur = 0;
    for (int j0 = 0; j0 < 1024; j0 += 64) {
        ushort* Kc = Ks0 + cur * 4096;
        ushort* Vc = Vs0 + cur * 4096;
        if (j0 < 960) {
            int nx = cur ^ 1;
            int c = pc ^ (srow & 7);
            gl_lds16(&kTb[(size_t)(j0 + 64 + srow) * 512 + c * 8], &Ks0[nx * 4096 + t * 8]);
            gl_lds16(&vb[(size_t)srow * 1024 + j0 + 64 + c * 8],   &Vs0[nx * 4096 + t * 8]);
        }
        // QK^T for this wave's j-half: S rows j = jw*32 + (r&3)+8*(r>>2)+4*hf
        f32x16 s = {};
        __builtin_amdgcn_s_setprio(1);
#pragma unroll
        for (int ks = 0; ks < 4; ++ks) {
            int row = jw * 32 + l31;
            int c = (2 * ks + hf) ^ (row & 7);
            bf16x8 ak = *(const bf16x8*)&Kc[row * 64 + c * 8];
            s = __builtin_amdgcn_mfma_f32_32x32x16_bf16(ak, qf[ks], s, 0, 0, 0);
        }
        __builtin_amdgcn_s_setprio(0);
        // exp + pack (fused, short live ranges) + row-sum accumulate
        uint w0[4], w1[4];
#pragma unroll
        for (int q = 0; q < 4; ++q) {
            float e0 = EXP2F(s[q * 4 + 0]), e1 = EXP2F(s[q * 4 + 1]);
            float e2 = EXP2F(s[q * 4 + 2]), e3 = EXP2F(s[q * 4 + 3]);
            lsum += (e0 + e1) + (e2 + e3);
            w0[q] = cvt2(e0, e1);
            w1[q] = cvt2(e2, e3);
        }
        bf16x8 pf[2];
#pragma unroll
        for (int s2 = 0; s2 < 2; ++s2) {
            uint2v ra = plswap(w0[2 * s2], w0[2 * s2 + 1]);
            uint2v rb = plswap(w1[2 * s2], w1[2 * s2 + 1]);
            uint4 u; u.x = ra.x; u.y = rb.x; u.z = ra.y; u.w = rb.y;
            bf16x8 v; __builtin_memcpy(&v, &u, 16);
            pf[s2] = v;
        }
        // PV: O^T[d][i] += V^T[d][j-half] * P[j-half][i]
        __builtin_amdgcn_s_setprio(1);
#pragma unroll
        for (int s2 = 0; s2 < 2; ++s2) {
#pragma unroll
            for (int db = 0; db < 2; ++db) {
                int row = db * 32 + l31;
                int c = (2 * (jw * 2 + s2) + hf) ^ (row & 7);
                bf16x8 av = *(const bf16x8*)&Vc[row * 64 + c * 8];
                if (db == 0)
                    oT0 = __builtin_amdgcn_mfma_f32_32x32x16_bf16(av, pf[s2], oT0, 0, 0, 0);
                else
                    oT1 = __builtin_amdgcn_mfma_f32_32x32x16_bf16(av, pf[s2], oT1, 0, 0, 0);
            }
        }
        __builtin_amdgcn_s_setprio(0);
        __syncthreads();
        cur ^= 1;
    }
    lsum += __shfl_xor(lsum, 32);
    // cross-jw reduce: jw=1 dumps O-partials + lsum to LDS, jw=0 accumulates
    float* OB = (float*)SM;   // [iw 4][d 64][i 32] f32 = 32KB (K/V dead)
    if (jw == 1) {
        float* ob = OB + iw * 2048;
#pragma unroll
        for (int r = 0; r < 16; ++r) {
            int d = (r & 3) + 8 * (r >> 2) + 4 * hf;
            ob[d * 32 + l31]        = oT0[r];
            ob[(d + 32) * 32 + l31] = oT1[r];
        }
        if (lane < 32) LS[iw][l31] = lsum;
    }
    __syncthreads();
    if (jw == 0) {
        float* ob = OB + iw * 2048;
#pragma unroll
        for (int r = 0; r < 16; ++r) {
            int d = (r & 3) + 8 * (r >> 2) + 4 * hf;
            oT0[r] += ob[d * 32 + l31];
            oT1[r] += ob[(d + 32) * 32 + l31];
        }
        lsum += LS[iw][l31];
    }
    __syncthreads();   // OB region about to be reused as transpose buffer
    if (jw == 0) {
        float linv = 1.f / lsum;
        uint* Os = (uint*)SM + iw * (32 * 33);   // 4 waves x 4.1KB
#pragma unroll
        for (int db = 0; db < 2; ++db) {
            f32x16 ov = (db == 0) ? oT0 : oT1;
#pragma unroll
            for (int q = 0; q < 4; ++q) {
                uint wa  = cvt2(ov[q * 4 + 0] * linv, ov[q * 4 + 1] * linv);
                uint wb2 = cvt2(ov[q * 4 + 2] * linv, ov[q * 4 + 3] * linv);
                int base = l31 * 33 + db * 16 + q * 4 + 2 * hf;
                Os[base]     = wa;
                Os[base + 1] = wb2;
            }
        }
        __asm__ __volatile__("" ::: "memory");
#pragma unroll
        for (int rr = 0; rr < 4; ++rr) {
            int irow = (lane >> 3) + rr * 8;
            const uint* rp = &Os[irow * 33 + (lane & 7) * 4];
            uint4 u; u.x = rp[0]; u.y = rp[1]; u.z = rp[2]; u.w = rp[3];
            *(uint4*)&ot[((size_t)b * 1024 + i0 + iw * 32 + irow) * 256 + h * 64 + (lane & 7) * 8] = u;
        }
    }
}

// ---------------------------------------------------------------------------
// K5: proj GEMM + bias + residual (unchanged). 64(sp) x 128(chan) tiles,
// BK=64 async dbuf, 48KB LDS. 4 waves: 2(chan) x 2(sp), acc[4][2].
// ---------------------------------------------------------------------------
__global__ __launch_bounds__(256, 3) void proj_k(
    const ushort* __restrict__ pwb, const ushort* __restrict__ ot,
    const float* __restrict__ pb, const float* __restrict__ x,
    float* __restrict__ out) {
    int b = blockIdx.z, cy = blockIdx.y, sx = blockIdx.x;
    __shared__ ushort SB[2][12288];  // [buf][ W 128*64 | X 64*64 ] = 48KB
    int t = threadIdx.x, lane = t & 63, w = t >> 6;
    int quad = lane >> 4, l15 = lane & 15;
    int wm = w >> 1, wn = w & 1;
    const ushort* wrow = pwb + (size_t)cy * 128 * 256;
    const ushort* xrow = ot + ((size_t)b * 1024 + sx * 64) * 256;
    int r0 = t >> 3;
    int cs = (t & 7) ^ (r0 & 7);
    int dst = t * 8;
#pragma unroll
    for (int ps = 0; ps < 4; ++ps)
        gl_lds16(&wrow[(size_t)(r0 + ps * 32) * 256 + cs * 8], &SB[0][ps * 2048 + dst]);
#pragma unroll
    for (int ps = 0; ps < 2; ++ps)
        gl_lds16(&xrow[(size_t)(r0 + ps * 32) * 256 + cs * 8], &SB[0][8192 + ps * 2048 + dst]);
    __syncthreads();
    int p0 = quad ^ (l15 & 7);
    f32x4 acc[4][2] = {};
    int cur = 0;
    for (int ki = 0; ki < 4; ++ki) {
        if (ki < 3) {
            int k0 = (ki + 1) * 64, nx = cur ^ 1;
#pragma unroll
            for (int ps = 0; ps < 4; ++ps)
                gl_lds16(&wrow[(size_t)(r0 + ps * 32) * 256 + k0 + cs * 8], &SB[nx][ps * 2048 + dst]);
#pragma unroll
            for (int ps = 0; ps < 2; ++ps)
                gl_lds16(&xrow[(size_t)(r0 + ps * 32) * 256 + k0 + cs * 8], &SB[nx][8192 + ps * 2048 + dst]);
        }
        const ushort* Wc = &SB[cur][0];
        const ushort* Xc = &SB[cur][8192];
#pragma unroll
        for (int kk = 0; kk < 2; ++kk) {
            int sl = p0 ^ (kk * 4);
            bf16x8 fa[4], fb[2];
#pragma unroll
            for (int mi = 0; mi < 4; ++mi)
                fa[mi] = *(const bf16x8*)&Wc[(wm * 64 + mi * 16 + l15) * 64 + sl * 8];
#pragma unroll
            for (int ni = 0; ni < 2; ++ni)
                fb[ni] = *(const bf16x8*)&Xc[(wn * 32 + ni * 16 + l15) * 64 + sl * 8];
#pragma unroll
            for (int mi = 0; mi < 4; ++mi)
#pragma unroll
                for (int ni = 0; ni < 2; ++ni)
                    acc[mi][ni] = __builtin_amdgcn_mfma_f32_16x16x32_bf16(
                        fa[mi], fb[ni], acc[mi][ni], 0, 0, 0);
        }
        __syncthreads();
        cur ^= 1;
    }
#pragma unroll
    for (int mi = 0; mi < 4; ++mi)
#pragma unroll
        for (int rr = 0; rr < 4; ++rr) {
            int chan = cy * 128 + wm * 64 + mi * 16 + quad * 4 + rr;
            float bias = pb[chan];
#pragma unroll
            for (int ni = 0; ni < 2; ++ni) {
                int sp = sx * 64 + wn * 32 + ni * 16 + l15;
                size_t o = ((size_t)(b * 256 + chan)) * 1024 + sp;
                out[o] = acc[mi][ni][rr] + bias + x[o];
            }
        }
}

// ---------------------------------------------------------------------------
extern "C" void kernel_launch(void* const* d_in, const int* in_sizes, int n_in,
                              void* d_out, int out_size, void* d_ws, size_t ws_size,
                              hipStream_t stream) {
    const float* x    = (const float*)d_in[0];
    const float* nw   = (const float*)d_in[1];
    const float* nb   = (const float*)d_in[2];
    const float* qkvw = (const float*)d_in[3];
    const float* qkvb = (const float*)d_in[4];
    const float* pw   = (const float*)d_in[5];
    const float* pb   = (const float*)d_in[6];
    float* out = (float*)d_out;

    // Workspace (~34 MB): xt | wqb | pwb | qkT | vbuf; ot aliases xt.
    ushort* base = (ushort*)d_ws;
    ushort* xt   = base;                          // 16*1024*256
    ushort* wqb  = xt + (size_t)16 * 1024 * 256;  // 768*256
    ushort* pwb  = wqb + 768 * 256;               // 256*256
    ushort* qkT  = pwb + 256 * 256;               // 16*1024*512
    ushort* vbuf = qkT + (size_t)16 * 1024 * 512; // 16*256*1024
    ushort* ot   = xt;                            // reuse

    norm_k<<<dim3(192), dim3(1024), 0, stream>>>(x, nw, nb, qkvw, pw, xt, wqb, pwb);
    qkv_gemm_k<<<dim3(8, 6, Bc), dim3(256), 0, stream>>>(wqb, xt, qkvb, qkT, vbuf);
    attn_k<<<dim3(64, 8), dim3(512), 0, stream>>>(qkT, vbuf, ot);
    proj_k<<<dim3(16, 2, Bc), dim3(256), 0, stream>>>(pwb, ot, pb, x, out);
}

// Round 5
// 129.276 us; speedup vs baseline: 1.0078x; 1.0078x over previous
//
#include <hip/hip_runtime.h>
#include <math.h>

typedef unsigned short ushort;
typedef unsigned int uint;
typedef __attribute__((ext_vector_type(8))) short bf16x8;
typedef __attribute__((ext_vector_type(4))) float f32x4;
typedef __attribute__((ext_vector_type(16))) float f32x16;
typedef __attribute__((ext_vector_type(2))) unsigned uint2v;

constexpr int Bc  = 16;
constexpr float EPSc = 1e-5f;
constexpr float QSC  = 0.18033688f;  // 0.125 * log2(e): softmax exp -> exp2

// v_cvt_pk_bf16_f32: one instr per bf16 pair (no builtin on gfx950)
__device__ __forceinline__ uint cvt2(float a, float b) {
    uint r;
    asm("v_cvt_pk_bf16_f32 %0, %1, %2" : "=v"(r) : "v"(a), "v"(b));
    return r;
}
__device__ __forceinline__ ushort f2bf_fast(float f) {
    uint r;
    asm("v_cvt_pk_bf16_f32 %0, %1, %2" : "=v"(r) : "v"(f), "v"(f));
    return (ushort)r;
}
// permlane32_swap: r.x = [a.lanes0-31 | b.lanes0-31], r.y = [a.lanes32-63 | b.lanes32-63]
__device__ __forceinline__ uint2v plswap(uint a, uint b) {
#if __has_builtin(__builtin_amdgcn_permlane32_swap)
    return __builtin_amdgcn_permlane32_swap(a, b, false, false);
#else
    asm volatile("v_permlane32_swap_b32 %0, %1" : "+v"(a), "+v"(b));
    uint2v r; r.x = a; r.y = b; return r;
#endif
}
#if __has_builtin(__builtin_amdgcn_exp2f)
#define EXP2F(x) __builtin_amdgcn_exp2f(x)
#else
#define EXP2F(x) __expf((x) * 0.69314718f)
#endif
__device__ __forceinline__ void gl_lds16(const ushort* g, ushort* l) {
    __builtin_amdgcn_global_load_lds(
        (const __attribute__((address_space(1))) void*)g,
        (__attribute__((address_space(3))) void*)l, 16, 0, 0);
}

// ---------------------------------------------------------------------------
// K1: fused GroupNorm, ONE-PASS: stage the 128KB (b,g) slice in LDS f32
// while accumulating stats; normalize straight out of LDS (no global
// re-read). Blocks 0..127: slices. Blocks 128..191: weight cvt.
// ---------------------------------------------------------------------------
__global__ __launch_bounds__(1024, 4) void norm_k(
    const float* __restrict__ x, const float* __restrict__ nw,
    const float* __restrict__ nb, const float* __restrict__ qkvw,
    const float* __restrict__ pw, ushort* __restrict__ xt,
    ushort* __restrict__ wqb, ushort* __restrict__ pwb) {
    __shared__ float XS[32768];   // 128KB: [c 32][n 1024]
    __shared__ float rs[16], rq[16], bc[2];
    int blk = blockIdx.x;
    int t = threadIdx.x;
    if (blk < 128) {
        int b = blk >> 3, g = blk & 7;
        const float* xs = x + ((size_t)(b * 8 + g)) * 32768;
        const float4* p4 = (const float4*)xs;
        float s = 0.f, s2 = 0.f;
#pragma unroll
        for (int i = 0; i < 8; ++i) {
            float4 v = p4[t + i * 1024];
            s += (v.x + v.y) + (v.z + v.w);
            s2 += (v.x * v.x + v.y * v.y) + (v.z * v.z + v.w * v.w);
            *(float4*)&XS[(t + i * 1024) * 4] = v;
        }
#pragma unroll
        for (int off = 1; off < 64; off <<= 1) {
            s += __shfl_xor(s, off);
            s2 += __shfl_xor(s2, off);
        }
        int wv = t >> 6, lane = t & 63;
        if (lane == 0) { rs[wv] = s; rq[wv] = s2; }
        __syncthreads();
        if (t == 0) {
            float ts = 0.f, tq = 0.f;
#pragma unroll
            for (int i = 0; i < 16; ++i) { ts += rs[i]; tq += rq[i]; }
            float mean = ts * (1.f / 32768.f);
            float var  = tq * (1.f / 32768.f) - mean * mean;
            bc[0] = mean; bc[1] = rsqrtf(var + EPSc);
        }
        __syncthreads();
        float mean = bc[0], inv = bc[1];
        int n = t;
        uint w[16];
#pragma unroll
        for (int c = 0; c < 32; c += 2) {
            float w0 = inv * nw[g * 32 + c];
            float b0 = nb[g * 32 + c] - mean * w0;
            float w1 = inv * nw[g * 32 + c + 1];
            float b1 = nb[g * 32 + c + 1] - mean * w1;
            float v0 = XS[c * 1024 + n] * w0 + b0;
            float v1 = XS[(c + 1) * 1024 + n] * w1 + b1;
            w[c >> 1] = cvt2(v0, v1);
        }
        ushort* dst = &xt[((size_t)(b * 1024 + n)) * 256 + g * 32];
#pragma unroll
        for (int i = 0; i < 4; ++i) {
            uint4 u; u.x = w[i*4]; u.y = w[i*4+1]; u.z = w[i*4+2]; u.w = w[i*4+3];
            *(uint4*)&dst[i * 8] = u;
        }
    } else {
        int idx = ((blk - 128) * 1024 + t) * 4;
        if (idx < 196608) {
            int row = idx >> 8;
            float sc = (row < 256) ? QSC : 1.f;
            float4 v = *(const float4*)&qkvw[idx];
            uint2 u; u.x = cvt2(v.x * sc, v.y * sc); u.y = cvt2(v.z * sc, v.w * sc);
            *(uint2*)&wqb[idx] = u;
        } else {
            int j = idx - 196608;
            float4 v = *(const float4*)&pw[j];
            uint2 u; u.x = cvt2(v.x, v.y); u.y = cvt2(v.z, v.w);
            *(uint2*)&pwb[j] = u;
        }
    }
}

// ---------------------------------------------------------------------------
// K3: qkv GEMM (unchanged, proven): BK=64 async dbuf, 1 barrier/iter.
// 128x128 tile, 4 waves. cy 0..3 -> qkT transposed; cy 4..5 -> vbuf natural.
// ---------------------------------------------------------------------------
__global__ __launch_bounds__(256, 2) void qkv_gemm_k(
    const ushort* __restrict__ wq, const ushort* __restrict__ xt,
    const float* __restrict__ wb, ushort* __restrict__ qkT,
    ushort* __restrict__ vbuf) {
    int b = blockIdx.z, cy = blockIdx.y, sx = blockIdx.x;
    __shared__ ushort SB[2][2][128 * 64];
    int t = threadIdx.x, lane = t & 63, w = t >> 6;
    int quad = lane >> 4, l15 = lane & 15;
    int wm = w >> 1, wn = w & 1;
    const ushort* wrow = wq + (size_t)cy * 128 * 256;
    const ushort* xrow = xt + ((size_t)b * 1024 + sx * 128) * 256;
    bool tpath = (cy < 4);
    int r0 = t >> 3;
    int cs = (t & 7) ^ (r0 & 7);
    int dst = t * 8;
#pragma unroll
    for (int ps = 0; ps < 4; ++ps) {
        int r = r0 + ps * 32;
        gl_lds16(&wrow[(size_t)r * 256 + cs * 8], &SB[0][0][ps * 2048 + dst]);
        gl_lds16(&xrow[(size_t)r * 256 + cs * 8], &SB[0][1][ps * 2048 + dst]);
    }
    __syncthreads();
    int s0 = quad ^ (l15 & 7);
    f32x4 acc[4][4] = {};
    int cur = 0;
    for (int ki = 0; ki < 4; ++ki) {
        if (ki < 3) {
            int k0 = (ki + 1) * 64, nx = cur ^ 1;
#pragma unroll
            for (int ps = 0; ps < 4; ++ps) {
                int r = r0 + ps * 32;
                gl_lds16(&wrow[(size_t)r * 256 + k0 + cs * 8], &SB[nx][0][ps * 2048 + dst]);
                gl_lds16(&xrow[(size_t)r * 256 + k0 + cs * 8], &SB[nx][1][ps * 2048 + dst]);
            }
        }
        const ushort* Wc = SB[cur][0];
        const ushort* Xc = SB[cur][1];
        const ushort* Am = tpath ? Xc : Wc;
        const ushort* Bn = tpath ? Wc : Xc;
#pragma unroll
        for (int kk = 0; kk < 2; ++kk) {
            int sl = s0 ^ (kk * 4);
            bf16x8 fa[4], fb[4];
#pragma unroll
            for (int mi = 0; mi < 4; ++mi)
                fa[mi] = *(const bf16x8*)&Am[(wm * 64 + mi * 16 + l15) * 64 + sl * 8];
#pragma unroll
            for (int ni = 0; ni < 4; ++ni)
                fb[ni] = *(const bf16x8*)&Bn[(wn * 64 + ni * 16 + l15) * 64 + sl * 8];
#pragma unroll
            for (int mi = 0; mi < 4; ++mi)
#pragma unroll
                for (int ni = 0; ni < 4; ++ni)
                    acc[mi][ni] = __builtin_amdgcn_mfma_f32_16x16x32_bf16(
                        fa[mi], fb[ni], acc[mi][ni], 0, 0, 0);
        }
        __syncthreads();
        cur ^= 1;
    }
    __syncthreads();
    ushort* Tw = ((ushort*)SB) + w * (64 * 72);
    float bsc = (tpath && cy < 2) ? QSC : 1.f;
    if (tpath) {
#pragma unroll
        for (int ni = 0; ni < 4; ++ni) {
            float bias = wb[cy * 128 + wn * 64 + ni * 16 + l15] * bsc;
#pragma unroll
            for (int mi = 0; mi < 4; ++mi)
#pragma unroll
                for (int rr = 0; rr < 4; ++rr)
                    Tw[(mi * 16 + quad * 4 + rr) * 72 + ni * 16 + l15] =
                        f2bf_fast(acc[mi][ni][rr] + bias);
        }
    } else {
#pragma unroll
        for (int mi = 0; mi < 4; ++mi)
#pragma unroll
            for (int rr = 0; rr < 4; ++rr) {
                float bias = wb[cy * 128 + wm * 64 + mi * 16 + quad * 4 + rr];
#pragma unroll
                for (int ni = 0; ni < 4; ++ni)
                    Tw[(mi * 16 + quad * 4 + rr) * 72 + ni * 16 + l15] =
                        f2bf_fast(acc[mi][ni][rr] + bias);
            }
    }
    __asm__ __volatile__("" ::: "memory");
    int row8 = lane >> 3, ch = lane & 7;
#pragma unroll
    for (int p = 0; p < 8; ++p) {
        int row = p * 8 + row8;
        uint4 u = *(const uint4*)&Tw[row * 72 + ch * 8];
        if (tpath) {
            int sp = sx * 128 + wm * 64 + row;
            *(uint4*)&qkT[((size_t)b * 1024 + sp) * 512 + cy * 128 + wn * 64 + ch * 8] = u;
        } else {
            int chanloc = (cy - 4) * 128 + wm * 64 + row;
            *(uint4*)&vbuf[((size_t)b * 256 + chanloc) * 1024 + sx * 128 + wn * 64 + ch * 8] = u;
        }
    }
}

// ---------------------------------------------------------------------------
// K4: flash attention (round-3 proven shape: 4 waves x 32 i-rows, each wave
// does the FULL j-range; 2 blocks/CU, 8 waves/CU) + round-5 change:
// j-tile 128 (double-size staging, 64KB LDS dbuf) -> barrier/drain count
// halves 16 -> 8 at the same work-per-barrier per wave (32 MFMA).
// K LDS: [buf][128 j][64 ch], row&7-XOR 8-chunk swizzle (stride 64).
// V LDS: [buf][64 ch][128 j], row&7-XOR 16-chunk swizzle (stride 128).
// Swapped QK (A=K, B=Q): S col=i per lane; in-register softmax;
// P->bf16 PV B-frags via cvt_pk + permlane32_swap; O computed transposed.
// ---------------------------------------------------------------------------
__global__ __launch_bounds__(256, 2) void attn_k(
    const ushort* __restrict__ qkT, const ushort* __restrict__ vbuf,
    ushort* __restrict__ ot) {
    int bh = blockIdx.x;
    int i0 = blockIdx.y * 128;
    int b = bh >> 2, h = bh & 3;
    const ushort* qTb = qkT + (size_t)b * 1024 * 512 + h * 64;
    const ushort* kTb = qTb + 256;
    const ushort* vb  = vbuf + ((size_t)(b * 256 + h * 64)) * 1024;
    __shared__ ushort SM[32768];          // Ks[2][8192] | Vs[2][8192] (64KB)
    ushort* Ks0 = SM;
    ushort* Vs0 = SM + 16384;
    int t = threadIdx.x, lane = t & 63, wv = t >> 6;
    int l31 = lane & 31, hf = lane >> 5;
    int rk = t >> 3, pk = t & 7;          // K staging: 32 rows x 8 chunks
    int rv = t >> 4, pv = t & 15;         // V staging: 16 rows x 16 chunks
    // stage j-tile 0: K 128x64, V 64x128
#pragma unroll
    for (int seg = 0; seg < 4; ++seg) {
        int krow = seg * 32 + rk;
        int kc = pk ^ (krow & 7);
        gl_lds16(&kTb[(size_t)krow * 512 + kc * 8], &Ks0[seg * 2048 + t * 8]);
        int vrow = seg * 16 + rv;
        int vc = pv ^ (vrow & 7);
        gl_lds16(&vb[(size_t)vrow * 1024 + vc * 8], &Vs0[seg * 2048 + t * 8]);
    }
    // Q frags direct from global: B-frag col=i=l31, k = ks*16 + hf*8 + e
    bf16x8 qf[4];
#pragma unroll
    for (int ks = 0; ks < 4; ++ks)
        qf[ks] = *(const bf16x8*)
            &qTb[(size_t)(i0 + wv * 32 + l31) * 512 + ks * 16 + hf * 8];
    __syncthreads();
    f32x16 oT0 = {}, oT1 = {};   // O^T[d][i], d-halves
    float lsum = 0.f;
    int cur = 0;
    for (int j0 = 0; j0 < 1024; j0 += 128) {
        ushort* Kc = Ks0 + cur * 8192;
        ushort* Vc = Vs0 + cur * 8192;
        if (j0 < 896) {
            int nx = cur ^ 1;
            ushort* Kn = Ks0 + nx * 8192;
            ushort* Vn = Vs0 + nx * 8192;
#pragma unroll
            for (int seg = 0; seg < 4; ++seg) {
                int krow = seg * 32 + rk;
                int kc = pk ^ (krow & 7);
                gl_lds16(&kTb[(size_t)(j0 + 128 + krow) * 512 + kc * 8], &Kn[seg * 2048 + t * 8]);
                int vrow = seg * 16 + rv;
                int vc = pv ^ (vrow & 7);
                gl_lds16(&vb[(size_t)vrow * 1024 + j0 + 128 + vc * 8], &Vn[seg * 2048 + t * 8]);
            }
        }
#pragma unroll
        for (int jb = 0; jb < 4; ++jb) {
            // QK^T: S[j][i], rows j = j0 + jb*32 + (r&3)+8*(r>>2)+4*hf, col i = l31
            f32x16 s = {};
            __builtin_amdgcn_s_setprio(1);
#pragma unroll
            for (int ks = 0; ks < 4; ++ks) {
                int row = jb * 32 + l31;
                int c = (2 * ks + hf) ^ (row & 7);
                bf16x8 ak = *(const bf16x8*)&Kc[row * 64 + c * 8];
                s = __builtin_amdgcn_mfma_f32_32x32x16_bf16(ak, qf[ks], s, 0, 0, 0);
            }
            __builtin_amdgcn_s_setprio(0);
            // exp + pack (fused) + row-sum accumulate
            uint w0[4], w1[4];
#pragma unroll
            for (int q = 0; q < 4; ++q) {
                float e0 = EXP2F(s[q * 4 + 0]), e1 = EXP2F(s[q * 4 + 1]);
                float e2 = EXP2F(s[q * 4 + 2]), e3 = EXP2F(s[q * 4 + 3]);
                lsum += (e0 + e1) + (e2 + e3);
                w0[q] = cvt2(e0, e1);
                w1[q] = cvt2(e2, e3);
            }
            bf16x8 pf[2];
#pragma unroll
            for (int s2 = 0; s2 < 2; ++s2) {
                uint2v ra = plswap(w0[2 * s2], w0[2 * s2 + 1]);
                uint2v rb = plswap(w1[2 * s2], w1[2 * s2 + 1]);
                uint4 u; u.x = ra.x; u.y = rb.x; u.z = ra.y; u.w = rb.y;
                bf16x8 v; __builtin_memcpy(&v, &u, 16);
                pf[s2] = v;
            }
            // PV: O^T[d][i] += V^T[d][j-slot] * P[j-slot][i]
            __builtin_amdgcn_s_setprio(1);
#pragma unroll
            for (int s2 = 0; s2 < 2; ++s2) {
#pragma unroll
                for (int db = 0; db < 2; ++db) {
                    int row = db * 32 + l31;
                    int c = (jb * 4 + s2 * 2 + hf) ^ (row & 7);
                    bf16x8 av = *(const bf16x8*)&Vc[row * 128 + c * 8];
                    if (db == 0)
                        oT0 = __builtin_amdgcn_mfma_f32_32x32x16_bf16(av, pf[s2], oT0, 0, 0, 0);
                    else
                        oT1 = __builtin_amdgcn_mfma_f32_32x32x16_bf16(av, pf[s2], oT1, 0, 0, 0);
                }
            }
            __builtin_amdgcn_s_setprio(0);
        }
        __syncthreads();
        cur ^= 1;
    }
    lsum += __shfl_xor(lsum, 32);
    float linv = 1.f / lsum;
    // epilogue: per-wave LDS transpose (stride-33 dwords), then coalesced store
    uint* Os = (uint*)SM + wv * (32 * 33);
#pragma unroll
    for (int db = 0; db < 2; ++db) {
        f32x16 ov = (db == 0) ? oT0 : oT1;
#pragma unroll
        for (int q = 0; q < 4; ++q) {
            uint wa  = cvt2(ov[q * 4 + 0] * linv, ov[q * 4 + 1] * linv);
            uint wb2 = cvt2(ov[q * 4 + 2] * linv, ov[q * 4 + 3] * linv);
            int base = l31 * 33 + db * 16 + q * 4 + 2 * hf;
            Os[base]     = wa;
            Os[base + 1] = wb2;
        }
    }
    __asm__ __volatile__("" ::: "memory");
#pragma unroll
    for (int rr = 0; rr < 4; ++rr) {
        int irow = (lane >> 3) + rr * 8;
        const uint* rp = &Os[irow * 33 + (lane & 7) * 4];
        uint4 u; u.x = rp[0]; u.y = rp[1]; u.z = rp[2]; u.w = rp[3];
        *(uint4*)&ot[((size_t)b * 1024 + i0 + wv * 32 + irow) * 256 + h * 64 + (lane & 7) * 8] = u;
    }
}

// ---------------------------------------------------------------------------
// K5: proj GEMM + bias + residual (unchanged). 64(sp) x 128(chan) tiles,
// BK=64 async dbuf, 48KB LDS. 4 waves: 2(chan) x 2(sp), acc[4][2].
// ---------------------------------------------------------------------------
__global__ __launch_bounds__(256, 3) void proj_k(
    const ushort* __restrict__ pwb, const ushort* __restrict__ ot,
    const float* __restrict__ pb, const float* __restrict__ x,
    float* __restrict__ out) {
    int b = blockIdx.z, cy = blockIdx.y, sx = blockIdx.x;
    __shared__ ushort SB[2][12288];  // [buf][ W 128*64 | X 64*64 ] = 48KB
    int t = threadIdx.x, lane = t & 63, w = t >> 6;
    int quad = lane >> 4, l15 = lane & 15;
    int wm = w >> 1, wn = w & 1;
    const ushort* wrow = pwb + (size_t)cy * 128 * 256;
    const ushort* xrow = ot + ((size_t)b * 1024 + sx * 64) * 256;
    int r0 = t >> 3;
    int cs = (t & 7) ^ (r0 & 7);
    int dst = t * 8;
#pragma unroll
    for (int ps = 0; ps < 4; ++ps)
        gl_lds16(&wrow[(size_t)(r0 + ps * 32) * 256 + cs * 8], &SB[0][ps * 2048 + dst]);
#pragma unroll
    for (int ps = 0; ps < 2; ++ps)
        gl_lds16(&xrow[(size_t)(r0 + ps * 32) * 256 + cs * 8], &SB[0][8192 + ps * 2048 + dst]);
    __syncthreads();
    int p0 = quad ^ (l15 & 7);
    f32x4 acc[4][2] = {};
    int cur = 0;
    for (int ki = 0; ki < 4; ++ki) {
        if (ki < 3) {
            int k0 = (ki + 1) * 64, nx = cur ^ 1;
#pragma unroll
            for (int ps = 0; ps < 4; ++ps)
                gl_lds16(&wrow[(size_t)(r0 + ps * 32) * 256 + k0 + cs * 8], &SB[nx][ps * 2048 + dst]);
#pragma unroll
            for (int ps = 0; ps < 2; ++ps)
                gl_lds16(&xrow[(size_t)(r0 + ps * 32) * 256 + k0 + cs * 8], &SB[nx][8192 + ps * 2048 + dst]);
        }
        const ushort* Wc = &SB[cur][0];
        const ushort* Xc = &SB[cur][8192];
#pragma unroll
        for (int kk = 0; kk < 2; ++kk) {
            int sl = p0 ^ (kk * 4);
            bf16x8 fa[4], fb[2];
#pragma unroll
            for (int mi = 0; mi < 4; ++mi)
                fa[mi] = *(const bf16x8*)&Wc[(wm * 64 + mi * 16 + l15) * 64 + sl * 8];
#pragma unroll
            for (int ni = 0; ni < 2; ++ni)
                fb[ni] = *(const bf16x8*)&Xc[(wn * 32 + ni * 16 + l15) * 64 + sl * 8];
#pragma unroll
            for (int mi = 0; mi < 4; ++mi)
#pragma unroll
                for (int ni = 0; ni < 2; ++ni)
                    acc[mi][ni] = __builtin_amdgcn_mfma_f32_16x16x32_bf16(
                        fa[mi], fb[ni], acc[mi][ni], 0, 0, 0);
        }
        __syncthreads();
        cur ^= 1;
    }
#pragma unroll
    for (int mi = 0; mi < 4; ++mi)
#pragma unroll
        for (int rr = 0; rr < 4; ++rr) {
            int chan = cy * 128 + wm * 64 + mi * 16 + quad * 4 + rr;
            float bias = pb[chan];
#pragma unroll
            for (int ni = 0; ni < 2; ++ni) {
                int sp = sx * 64 + wn * 32 + ni * 16 + l15;
                size_t o = ((size_t)(b * 256 + chan)) * 1024 + sp;
                out[o] = acc[mi][ni][rr] + bias + x[o];
            }
        }
}

// ---------------------------------------------------------------------------
extern "C" void kernel_launch(void* const* d_in, const int* in_sizes, int n_in,
                              void* d_out, int out_size, void* d_ws, size_t ws_size,
                              hipStream_t stream) {
    const float* x    = (const float*)d_in[0];
    const float* nw   = (const float*)d_in[1];
    const float* nb   = (const float*)d_in[2];
    const float* qkvw = (const float*)d_in[3];
    const float* qkvb = (const float*)d_in[4];
    const float* pw   = (const float*)d_in[5];
    const float* pb   = (const float*)d_in[6];
    float* out = (float*)d_out;

    // Workspace (~34 MB): xt | wqb | pwb | qkT | vbuf; ot aliases xt.
    ushort* base = (ushort*)d_ws;
    ushort* xt   = base;                          // 16*1024*256
    ushort* wqb  = xt + (size_t)16 * 1024 * 256;  // 768*256
    ushort* pwb  = wqb + 768 * 256;               // 256*256
    ushort* qkT  = pwb + 256 * 256;               // 16*1024*512
    ushort* vbuf = qkT + (size_t)16 * 1024 * 512; // 16*256*1024
    ushort* ot   = xt;                            // reuse

    norm_k<<<dim3(192), dim3(1024), 0, stream>>>(x, nw, nb, qkvw, pw, xt, wqb, pwb);
    qkv_gemm_k<<<dim3(8, 6, Bc), dim3(256), 0, stream>>>(wqb, xt, qkvb, qkT, vbuf);
    attn_k<<<dim3(64, 8), dim3(256), 0, stream>>>(qkT, vbuf, ot);
    proj_k<<<dim3(16, 2, Bc), dim3(256), 0, stream>>>(pwb, ot, pb, x, out);
}

// Round 6
// 126.375 us; speedup vs baseline: 1.0309x; 1.0230x over previous
//
#include <hip/hip_runtime.h>
#include <math.h>

typedef unsigned short ushort;
typedef unsigned int uint;
typedef __attribute__((ext_vector_type(8))) short bf16x8;
typedef __attribute__((ext_vector_type(4))) float f32x4;
typedef __attribute__((ext_vector_type(16))) float f32x16;
typedef __attribute__((ext_vector_type(2))) unsigned uint2v;

constexpr int Bc  = 16;
constexpr float EPSc = 1e-5f;
constexpr float QSC  = 0.18033688f;  // 0.125 * log2(e): softmax exp -> exp2

// v_cvt_pk_bf16_f32: one instr per bf16 pair (no builtin on gfx950)
__device__ __forceinline__ uint cvt2(float a, float b) {
    uint r;
    asm("v_cvt_pk_bf16_f32 %0, %1, %2" : "=v"(r) : "v"(a), "v"(b));
    return r;
}
__device__ __forceinline__ ushort f2bf_fast(float f) {
    uint r;
    asm("v_cvt_pk_bf16_f32 %0, %1, %2" : "=v"(r) : "v"(f), "v"(f));
    return (ushort)r;
}
// permlane32_swap: r.x = [a.lanes0-31 | b.lanes0-31], r.y = [a.lanes32-63 | b.lanes32-63]
__device__ __forceinline__ uint2v plswap(uint a, uint b) {
#if __has_builtin(__builtin_amdgcn_permlane32_swap)
    return __builtin_amdgcn_permlane32_swap(a, b, false, false);
#else
    asm volatile("v_permlane32_swap_b32 %0, %1" : "+v"(a), "+v"(b));
    uint2v r; r.x = a; r.y = b; return r;
#endif
}
#if __has_builtin(__builtin_amdgcn_exp2f)
#define EXP2F(x) __builtin_amdgcn_exp2f(x)
#else
#define EXP2F(x) __expf((x) * 0.69314718f)
#endif
__device__ __forceinline__ void gl_lds16(const ushort* g, ushort* l) {
    __builtin_amdgcn_global_load_lds(
        (const __attribute__((address_space(1))) void*)g,
        (__attribute__((address_space(3))) void*)l, 16, 0, 0);
}

// ---------------------------------------------------------------------------
// K1: fused GroupNorm (R3 two-pass form, proven fastest): stats pass from
// global (coalesced float4), then re-read the L2-hot slice in transposed-
// gather order and write xt[b][n][c] bf16. NO LDS staging (m-c #7: the
// slice is L2-resident; LDS one-pass serialized and cost +3us in R4/R5).
// Blocks 0..127: one (b,g) slice each. Blocks 128..191: weight cvt.
// ---------------------------------------------------------------------------
__global__ __launch_bounds__(1024, 4) void norm_k(
    const float* __restrict__ x, const float* __restrict__ nw,
    const float* __restrict__ nb, const float* __restrict__ qkvw,
    const float* __restrict__ pw, ushort* __restrict__ xt,
    ushort* __restrict__ wqb, ushort* __restrict__ pwb) {
    int blk = blockIdx.x;
    int t = threadIdx.x;
    if (blk < 128) {
        int b = blk >> 3, g = blk & 7;
        const float* xs = x + ((size_t)(b * 8 + g)) * 32768;
        const float4* p4 = (const float4*)xs;
        float s = 0.f, s2 = 0.f;
#pragma unroll
        for (int i = 0; i < 8; ++i) {
            float4 v = p4[t + i * 1024];
            s += (v.x + v.y) + (v.z + v.w);
            s2 += (v.x * v.x + v.y * v.y) + (v.z * v.z + v.w * v.w);
        }
#pragma unroll
        for (int off = 1; off < 64; off <<= 1) {
            s += __shfl_xor(s, off);
            s2 += __shfl_xor(s2, off);
        }
        __shared__ float rs[16], rq[16], bc[2];
        int wv = t >> 6, lane = t & 63;
        if (lane == 0) { rs[wv] = s; rq[wv] = s2; }
        __syncthreads();
        if (t == 0) {
            float ts = 0.f, tq = 0.f;
#pragma unroll
            for (int i = 0; i < 16; ++i) { ts += rs[i]; tq += rq[i]; }
            float mean = ts * (1.f / 32768.f);
            float var  = tq * (1.f / 32768.f) - mean * mean;
            bc[0] = mean; bc[1] = rsqrtf(var + EPSc);
        }
        __syncthreads();
        float mean = bc[0], inv = bc[1];
        int n = t;
        uint w[16];
#pragma unroll
        for (int c = 0; c < 32; c += 2) {
            float w0 = inv * nw[g * 32 + c];
            float b0 = nb[g * 32 + c] - mean * w0;
            float w1 = inv * nw[g * 32 + c + 1];
            float b1 = nb[g * 32 + c + 1] - mean * w1;
            float v0 = xs[(size_t)c * 1024 + n] * w0 + b0;
            float v1 = xs[(size_t)(c + 1) * 1024 + n] * w1 + b1;
            w[c >> 1] = cvt2(v0, v1);
        }
        ushort* dst = &xt[((size_t)(b * 1024 + n)) * 256 + g * 32];
#pragma unroll
        for (int i = 0; i < 4; ++i) {
            uint4 u; u.x = w[i*4]; u.y = w[i*4+1]; u.z = w[i*4+2]; u.w = w[i*4+3];
            *(uint4*)&dst[i * 8] = u;
        }
    } else {
        int idx = ((blk - 128) * 1024 + t) * 4;
        if (idx < 196608) {
            int row = idx >> 8;
            float sc = (row < 256) ? QSC : 1.f;
            float4 v = *(const float4*)&qkvw[idx];
            uint2 u; u.x = cvt2(v.x * sc, v.y * sc); u.y = cvt2(v.z * sc, v.w * sc);
            *(uint2*)&wqb[idx] = u;
        } else {
            int j = idx - 196608;
            float4 v = *(const float4*)&pw[j];
            uint2 u; u.x = cvt2(v.x, v.y); u.y = cvt2(v.z, v.w);
            *(uint2*)&pwb[j] = u;
        }
    }
}

// ---------------------------------------------------------------------------
// K3: qkv GEMM (unchanged, proven): BK=64 async dbuf, 1 barrier/iter.
// 128x128 tile, 4 waves. cy 0..3 -> qkT transposed; cy 4..5 -> vbuf natural.
// ---------------------------------------------------------------------------
__global__ __launch_bounds__(256, 2) void qkv_gemm_k(
    const ushort* __restrict__ wq, const ushort* __restrict__ xt,
    const float* __restrict__ wb, ushort* __restrict__ qkT,
    ushort* __restrict__ vbuf) {
    int b = blockIdx.z, cy = blockIdx.y, sx = blockIdx.x;
    __shared__ ushort SB[2][2][128 * 64];
    int t = threadIdx.x, lane = t & 63, w = t >> 6;
    int quad = lane >> 4, l15 = lane & 15;
    int wm = w >> 1, wn = w & 1;
    const ushort* wrow = wq + (size_t)cy * 128 * 256;
    const ushort* xrow = xt + ((size_t)b * 1024 + sx * 128) * 256;
    bool tpath = (cy < 4);
    int r0 = t >> 3;
    int cs = (t & 7) ^ (r0 & 7);
    int dst = t * 8;
#pragma unroll
    for (int ps = 0; ps < 4; ++ps) {
        int r = r0 + ps * 32;
        gl_lds16(&wrow[(size_t)r * 256 + cs * 8], &SB[0][0][ps * 2048 + dst]);
        gl_lds16(&xrow[(size_t)r * 256 + cs * 8], &SB[0][1][ps * 2048 + dst]);
    }
    __syncthreads();
    int s0 = quad ^ (l15 & 7);
    f32x4 acc[4][4] = {};
    int cur = 0;
    for (int ki = 0; ki < 4; ++ki) {
        if (ki < 3) {
            int k0 = (ki + 1) * 64, nx = cur ^ 1;
#pragma unroll
            for (int ps = 0; ps < 4; ++ps) {
                int r = r0 + ps * 32;
                gl_lds16(&wrow[(size_t)r * 256 + k0 + cs * 8], &SB[nx][0][ps * 2048 + dst]);
                gl_lds16(&xrow[(size_t)r * 256 + k0 + cs * 8], &SB[nx][1][ps * 2048 + dst]);
            }
        }
        const ushort* Wc = SB[cur][0];
        const ushort* Xc = SB[cur][1];
        const ushort* Am = tpath ? Xc : Wc;
        const ushort* Bn = tpath ? Wc : Xc;
#pragma unroll
        for (int kk = 0; kk < 2; ++kk) {
            int sl = s0 ^ (kk * 4);
            bf16x8 fa[4], fb[4];
#pragma unroll
            for (int mi = 0; mi < 4; ++mi)
                fa[mi] = *(const bf16x8*)&Am[(wm * 64 + mi * 16 + l15) * 64 + sl * 8];
#pragma unroll
            for (int ni = 0; ni < 4; ++ni)
                fb[ni] = *(const bf16x8*)&Bn[(wn * 64 + ni * 16 + l15) * 64 + sl * 8];
#pragma unroll
            for (int mi = 0; mi < 4; ++mi)
#pragma unroll
                for (int ni = 0; ni < 4; ++ni)
                    acc[mi][ni] = __builtin_amdgcn_mfma_f32_16x16x32_bf16(
                        fa[mi], fb[ni], acc[mi][ni], 0, 0, 0);
        }
        __syncthreads();
        cur ^= 1;
    }
    __syncthreads();
    ushort* Tw = ((ushort*)SB) + w * (64 * 72);
    float bsc = (tpath && cy < 2) ? QSC : 1.f;
    if (tpath) {
#pragma unroll
        for (int ni = 0; ni < 4; ++ni) {
            float bias = wb[cy * 128 + wn * 64 + ni * 16 + l15] * bsc;
#pragma unroll
            for (int mi = 0; mi < 4; ++mi)
#pragma unroll
                for (int rr = 0; rr < 4; ++rr)
                    Tw[(mi * 16 + quad * 4 + rr) * 72 + ni * 16 + l15] =
                        f2bf_fast(acc[mi][ni][rr] + bias);
        }
    } else {
#pragma unroll
        for (int mi = 0; mi < 4; ++mi)
#pragma unroll
            for (int rr = 0; rr < 4; ++rr) {
                float bias = wb[cy * 128 + wm * 64 + mi * 16 + quad * 4 + rr];
#pragma unroll
                for (int ni = 0; ni < 4; ++ni)
                    Tw[(mi * 16 + quad * 4 + rr) * 72 + ni * 16 + l15] =
                        f2bf_fast(acc[mi][ni][rr] + bias);
            }
    }
    __asm__ __volatile__("" ::: "memory");
    int row8 = lane >> 3, ch = lane & 7;
#pragma unroll
    for (int p = 0; p < 8; ++p) {
        int row = p * 8 + row8;
        uint4 u = *(const uint4*)&Tw[row * 72 + ch * 8];
        if (tpath) {
            int sp = sx * 128 + wm * 64 + row;
            *(uint4*)&qkT[((size_t)b * 1024 + sp) * 512 + cy * 128 + wn * 64 + ch * 8] = u;
        } else {
            int chanloc = (cy - 4) * 128 + wm * 64 + row;
            *(uint4*)&vbuf[((size_t)b * 256 + chanloc) * 1024 + sx * 128 + wn * 64 + ch * 8] = u;
        }
    }
}

// ---------------------------------------------------------------------------
// K4: flash attention (unchanged from R5): 4 waves x 32 i-rows, full
// j-range per wave, j-tile 128 (64KB LDS dbuf, 8 barriers), 2 blocks/CU.
// Swapped QK (A=K, B=Q): in-register softmax; P->bf16 via cvt_pk +
// permlane32_swap; O computed transposed.
// ---------------------------------------------------------------------------
__global__ __launch_bounds__(256, 2) void attn_k(
    const ushort* __restrict__ qkT, const ushort* __restrict__ vbuf,
    ushort* __restrict__ ot) {
    int bh = blockIdx.x;
    int i0 = blockIdx.y * 128;
    int b = bh >> 2, h = bh & 3;
    const ushort* qTb = qkT + (size_t)b * 1024 * 512 + h * 64;
    const ushort* kTb = qTb + 256;
    const ushort* vb  = vbuf + ((size_t)(b * 256 + h * 64)) * 1024;
    __shared__ ushort SM[32768];          // Ks[2][8192] | Vs[2][8192] (64KB)
    ushort* Ks0 = SM;
    ushort* Vs0 = SM + 16384;
    int t = threadIdx.x, lane = t & 63, wv = t >> 6;
    int l31 = lane & 31, hf = lane >> 5;
    int rk = t >> 3, pk = t & 7;          // K staging: 32 rows x 8 chunks
    int rv = t >> 4, pv = t & 15;         // V staging: 16 rows x 16 chunks
    // stage j-tile 0: K 128x64, V 64x128
#pragma unroll
    for (int seg = 0; seg < 4; ++seg) {
        int krow = seg * 32 + rk;
        int kc = pk ^ (krow & 7);
        gl_lds16(&kTb[(size_t)krow * 512 + kc * 8], &Ks0[seg * 2048 + t * 8]);
        int vrow = seg * 16 + rv;
        int vc = pv ^ (vrow & 7);
        gl_lds16(&vb[(size_t)vrow * 1024 + vc * 8], &Vs0[seg * 2048 + t * 8]);
    }
    // Q frags direct from global: B-frag col=i=l31, k = ks*16 + hf*8 + e
    bf16x8 qf[4];
#pragma unroll
    for (int ks = 0; ks < 4; ++ks)
        qf[ks] = *(const bf16x8*)
            &qTb[(size_t)(i0 + wv * 32 + l31) * 512 + ks * 16 + hf * 8];
    __syncthreads();
    f32x16 oT0 = {}, oT1 = {};   // O^T[d][i], d-halves
    float lsum = 0.f;
    int cur = 0;
    for (int j0 = 0; j0 < 1024; j0 += 128) {
        ushort* Kc = Ks0 + cur * 8192;
        ushort* Vc = Vs0 + cur * 8192;
        if (j0 < 896) {
            int nx = cur ^ 1;
            ushort* Kn = Ks0 + nx * 8192;
            ushort* Vn = Vs0 + nx * 8192;
#pragma unroll
            for (int seg = 0; seg < 4; ++seg) {
                int krow = seg * 32 + rk;
                int kc = pk ^ (krow & 7);
                gl_lds16(&kTb[(size_t)(j0 + 128 + krow) * 512 + kc * 8], &Kn[seg * 2048 + t * 8]);
                int vrow = seg * 16 + rv;
                int vc = pv ^ (vrow & 7);
                gl_lds16(&vb[(size_t)vrow * 1024 + j0 + 128 + vc * 8], &Vn[seg * 2048 + t * 8]);
            }
        }
#pragma unroll
        for (int jb = 0; jb < 4; ++jb) {
            // QK^T: S[j][i], rows j = j0 + jb*32 + (r&3)+8*(r>>2)+4*hf, col i = l31
            f32x16 s = {};
            __builtin_amdgcn_s_setprio(1);
#pragma unroll
            for (int ks = 0; ks < 4; ++ks) {
                int row = jb * 32 + l31;
                int c = (2 * ks + hf) ^ (row & 7);
                bf16x8 ak = *(const bf16x8*)&Kc[row * 64 + c * 8];
                s = __builtin_amdgcn_mfma_f32_32x32x16_bf16(ak, qf[ks], s, 0, 0, 0);
            }
            __builtin_amdgcn_s_setprio(0);
            // exp + pack (fused) + row-sum accumulate
            uint w0[4], w1[4];
#pragma unroll
            for (int q = 0; q < 4; ++q) {
                float e0 = EXP2F(s[q * 4 + 0]), e1 = EXP2F(s[q * 4 + 1]);
                float e2 = EXP2F(s[q * 4 + 2]), e3 = EXP2F(s[q * 4 + 3]);
                lsum += (e0 + e1) + (e2 + e3);
                w0[q] = cvt2(e0, e1);
                w1[q] = cvt2(e2, e3);
            }
            bf16x8 pf[2];
#pragma unroll
            for (int s2 = 0; s2 < 2; ++s2) {
                uint2v ra = plswap(w0[2 * s2], w0[2 * s2 + 1]);
                uint2v rb = plswap(w1[2 * s2], w1[2 * s2 + 1]);
                uint4 u; u.x = ra.x; u.y = rb.x; u.z = ra.y; u.w = rb.y;
                bf16x8 v; __builtin_memcpy(&v, &u, 16);
                pf[s2] = v;
            }
            // PV: O^T[d][i] += V^T[d][j-slot] * P[j-slot][i]
            __builtin_amdgcn_s_setprio(1);
#pragma unroll
            for (int s2 = 0; s2 < 2; ++s2) {
#pragma unroll
                for (int db = 0; db < 2; ++db) {
                    int row = db * 32 + l31;
                    int c = (jb * 4 + s2 * 2 + hf) ^ (row & 7);
                    bf16x8 av = *(const bf16x8*)&Vc[row * 128 + c * 8];
                    if (db == 0)
                        oT0 = __builtin_amdgcn_mfma_f32_32x32x16_bf16(av, pf[s2], oT0, 0, 0, 0);
                    else
                        oT1 = __builtin_amdgcn_mfma_f32_32x32x16_bf16(av, pf[s2], oT1, 0, 0, 0);
                }
            }
            __builtin_amdgcn_s_setprio(0);
        }
        __syncthreads();
        cur ^= 1;
    }
    lsum += __shfl_xor(lsum, 32);
    float linv = 1.f / lsum;
    // epilogue: per-wave LDS transpose (stride-33 dwords), then coalesced store
    uint* Os = (uint*)SM + wv * (32 * 33);
#pragma unroll
    for (int db = 0; db < 2; ++db) {
        f32x16 ov = (db == 0) ? oT0 : oT1;
#pragma unroll
        for (int q = 0; q < 4; ++q) {
            uint wa  = cvt2(ov[q * 4 + 0] * linv, ov[q * 4 + 1] * linv);
            uint wb2 = cvt2(ov[q * 4 + 2] * linv, ov[q * 4 + 3] * linv);
            int base = l31 * 33 + db * 16 + q * 4 + 2 * hf;
            Os[base]     = wa;
            Os[base + 1] = wb2;
        }
    }
    __asm__ __volatile__("" ::: "memory");
#pragma unroll
    for (int rr = 0; rr < 4; ++rr) {
        int irow = (lane >> 3) + rr * 8;
        const uint* rp = &Os[irow * 33 + (lane & 7) * 4];
        uint4 u; u.x = rp[0]; u.y = rp[1]; u.z = rp[2]; u.w = rp[3];
        *(uint4*)&ot[((size_t)b * 1024 + i0 + wv * 32 + irow) * 256 + h * 64 + (lane & 7) * 8] = u;
    }
}

// ---------------------------------------------------------------------------
// K5: proj GEMM + bias + residual (unchanged). 64(sp) x 128(chan) tiles,
// BK=64 async dbuf, 48KB LDS. 4 waves: 2(chan) x 2(sp), acc[4][2].
// ---------------------------------------------------------------------------
__global__ __launch_bounds__(256, 3) void proj_k(
    const ushort* __restrict__ pwb, const ushort* __restrict__ ot,
    const float* __restrict__ pb, const float* __restrict__ x,
    float* __restrict__ out) {
    int b = blockIdx.z, cy = blockIdx.y, sx = blockIdx.x;
    __shared__ ushort SB[2][12288];  // [buf][ W 128*64 | X 64*64 ] = 48KB
    int t = threadIdx.x, lane = t & 63, w = t >> 6;
    int quad = lane >> 4, l15 = lane & 15;
    int wm = w >> 1, wn = w & 1;
    const ushort* wrow = pwb + (size_t)cy * 128 * 256;
    const ushort* xrow = ot + ((size_t)b * 1024 + sx * 64) * 256;
    int r0 = t >> 3;
    int cs = (t & 7) ^ (r0 & 7);
    int dst = t * 8;
#pragma unroll
    for (int ps = 0; ps < 4; ++ps)
        gl_lds16(&wrow[(size_t)(r0 + ps * 32) * 256 + cs * 8], &SB[0][ps * 2048 + dst]);
#pragma unroll
    for (int ps = 0; ps < 2; ++ps)
        gl_lds16(&xrow[(size_t)(r0 + ps * 32) * 256 + cs * 8], &SB[0][8192 + ps * 2048 + dst]);
    __syncthreads();
    int p0 = quad ^ (l15 & 7);
    f32x4 acc[4][2] = {};
    int cur = 0;
    for (int ki = 0; ki < 4; ++ki) {
        if (ki < 3) {
            int k0 = (ki + 1) * 64, nx = cur ^ 1;
#pragma unroll
            for (int ps = 0; ps < 4; ++ps)
                gl_lds16(&wrow[(size_t)(r0 + ps * 32) * 256 + k0 + cs * 8], &SB[nx][ps * 2048 + dst]);
#pragma unroll
            for (int ps = 0; ps < 2; ++ps)
                gl_lds16(&xrow[(size_t)(r0 + ps * 32) * 256 + k0 + cs * 8], &SB[nx][8192 + ps * 2048 + dst]);
        }
        const ushort* Wc = &SB[cur][0];
        const ushort* Xc = &SB[cur][8192];
#pragma unroll
        for (int kk = 0; kk < 2; ++kk) {
            int sl = p0 ^ (kk * 4);
            bf16x8 fa[4], fb[2];
#pragma unroll
            for (int mi = 0; mi < 4; ++mi)
                fa[mi] = *(const bf16x8*)&Wc[(wm * 64 + mi * 16 + l15) * 64 + sl * 8];
#pragma unroll
            for (int ni = 0; ni < 2; ++ni)
                fb[ni] = *(const bf16x8*)&Xc[(wn * 32 + ni * 16 + l15) * 64 + sl * 8];
#pragma unroll
            for (int mi = 0; mi < 4; ++mi)
#pragma unroll
                for (int ni = 0; ni < 2; ++ni)
                    acc[mi][ni] = __builtin_amdgcn_mfma_f32_16x16x32_bf16(
                        fa[mi], fb[ni], acc[mi][ni], 0, 0, 0);
        }
        __syncthreads();
        cur ^= 1;
    }
#pragma unroll
    for (int mi = 0; mi < 4; ++mi)
#pragma unroll
        for (int rr = 0; rr < 4; ++rr) {
            int chan = cy * 128 + wm * 64 + mi * 16 + quad * 4 + rr;
            float bias = pb[chan];
#pragma unroll
            for (int ni = 0; ni < 2; ++ni) {
                int sp = sx * 64 + wn * 32 + ni * 16 + l15;
                size_t o = ((size_t)(b * 256 + chan)) * 1024 + sp;
                out[o] = acc[mi][ni][rr] + bias + x[o];
            }
        }
}

// ---------------------------------------------------------------------------
extern "C" void kernel_launch(void* const* d_in, const int* in_sizes, int n_in,
                              void* d_out, int out_size, void* d_ws, size_t ws_size,
                              hipStream_t stream) {
    const float* x    = (const float*)d_in[0];
    const float* nw   = (const float*)d_in[1];
    const float* nb   = (const float*)d_in[2];
    const float* qkvw = (const float*)d_in[3];
    const float* qkvb = (const float*)d_in[4];
    const float* pw   = (const float*)d_in[5];
    const float* pb   = (const float*)d_in[6];
    float* out = (float*)d_out;

    // Workspace (~34 MB): xt | wqb | pwb | qkT | vbuf; ot aliases xt.
    ushort* base = (ushort*)d_ws;
    ushort* xt   = base;                          // 16*1024*256
    ushort* wqb  = xt + (size_t)16 * 1024 * 256;  // 768*256
    ushort* pwb  = wqb + 768 * 256;               // 256*256
    ushort* qkT  = pwb + 256 * 256;               // 16*1024*512
    ushort* vbuf = qkT + (size_t)16 * 1024 * 512; // 16*256*1024
    ushort* ot   = xt;                            // reuse

    norm_k<<<dim3(192), dim3(1024), 0, stream>>>(x, nw, nb, qkvw, pw, xt, wqb, pwb);
    qkv_gemm_k<<<dim3(8, 6, Bc), dim3(256), 0, stream>>>(wqb, xt, qkvb, qkT, vbuf);
    attn_k<<<dim3(64, 8), dim3(256), 0, stream>>>(qkT, vbuf, ot);
    proj_k<<<dim3(16, 2, Bc), dim3(256), 0, stream>>>(pwb, ot, pb, x, out);
}

// Round 7
// 125.269 us; speedup vs baseline: 1.0400x; 1.0088x over previous
//
#include <hip/hip_runtime.h>
#include <math.h>

typedef unsigned short ushort;
typedef unsigned int uint;
typedef __attribute__((ext_vector_type(8))) short bf16x8;
typedef __attribute__((ext_vector_type(4))) float f32x4;
typedef __attribute__((ext_vector_type(16))) float f32x16;
typedef __attribute__((ext_vector_type(2))) unsigned uint2v;

constexpr int Bc  = 16;
constexpr float EPSc = 1e-5f;
constexpr float QSC  = 0.18033688f;  // 0.125 * log2(e): softmax exp -> exp2

// v_cvt_pk_bf16_f32: one instr per bf16 pair (no builtin on gfx950)
__device__ __forceinline__ uint cvt2(float a, float b) {
    uint r;
    asm("v_cvt_pk_bf16_f32 %0, %1, %2" : "=v"(r) : "v"(a), "v"(b));
    return r;
}
__device__ __forceinline__ ushort f2bf_fast(float f) {
    uint r;
    asm("v_cvt_pk_bf16_f32 %0, %1, %2" : "=v"(r) : "v"(f), "v"(f));
    return (ushort)r;
}
// permlane32_swap: r.x = [a.lanes0-31 | b.lanes0-31], r.y = [a.lanes32-63 | b.lanes32-63]
__device__ __forceinline__ uint2v plswap(uint a, uint b) {
#if __has_builtin(__builtin_amdgcn_permlane32_swap)
    return __builtin_amdgcn_permlane32_swap(a, b, false, false);
#else
    asm volatile("v_permlane32_swap_b32 %0, %1" : "+v"(a), "+v"(b));
    uint2v r; r.x = a; r.y = b; return r;
#endif
}
#if __has_builtin(__builtin_amdgcn_exp2f)
#define EXP2F(x) __builtin_amdgcn_exp2f(x)
#else
#define EXP2F(x) __expf((x) * 0.69314718f)
#endif
__device__ __forceinline__ void gl_lds16(const ushort* g, ushort* l) {
    __builtin_amdgcn_global_load_lds(
        (const __attribute__((address_space(1))) void*)g,
        (__attribute__((address_space(3))) void*)l, 16, 0, 0);
}

// ---------------------------------------------------------------------------
// K1: fused GroupNorm (two-pass, proven): stats pass from global (coalesced
// float4), then L2-hot re-read. Round-7: pass 2 VECTORIZED (G13) — each
// thread owns 4 consecutive n x 8 channels: 8x float4 loads (16B/lane)
// instead of 32 scalar 4B loads. Writes unchanged in traffic (4x uint4).
// Blocks 0..127: one (b,g) slice each. Blocks 128..191: weight cvt.
// ---------------------------------------------------------------------------
__global__ __launch_bounds__(1024, 4) void norm_k(
    const float* __restrict__ x, const float* __restrict__ nw,
    const float* __restrict__ nb, const float* __restrict__ qkvw,
    const float* __restrict__ pw, ushort* __restrict__ xt,
    ushort* __restrict__ wqb, ushort* __restrict__ pwb) {
    int blk = blockIdx.x;
    int t = threadIdx.x;
    if (blk < 128) {
        int b = blk >> 3, g = blk & 7;
        const float* xs = x + ((size_t)(b * 8 + g)) * 32768;
        const float4* p4 = (const float4*)xs;
        float s = 0.f, s2 = 0.f;
#pragma unroll
        for (int i = 0; i < 8; ++i) {
            float4 v = p4[t + i * 1024];
            s += (v.x + v.y) + (v.z + v.w);
            s2 += (v.x * v.x + v.y * v.y) + (v.z * v.z + v.w * v.w);
        }
#pragma unroll
        for (int off = 1; off < 64; off <<= 1) {
            s += __shfl_xor(s, off);
            s2 += __shfl_xor(s2, off);
        }
        __shared__ float rs[16], rq[16], bc[2];
        int wv = t >> 6, lane = t & 63;
        if (lane == 0) { rs[wv] = s; rq[wv] = s2; }
        __syncthreads();
        if (t == 0) {
            float ts = 0.f, tq = 0.f;
#pragma unroll
            for (int i = 0; i < 16; ++i) { ts += rs[i]; tq += rq[i]; }
            float mean = ts * (1.f / 32768.f);
            float var  = tq * (1.f / 32768.f) - mean * mean;
            bc[0] = mean; bc[1] = rsqrtf(var + EPSc);
        }
        __syncthreads();
        float mean = bc[0], inv = bc[1];
        // pass 2: thread = (n-group t&255 -> 4 consecutive n) x (cg = t>>8 -> 8 chans)
        int n = (t & 255) * 4;
        int cg = (t >> 8) * 8;
        uint pk[4][4];   // [k in n][c-pair]
#pragma unroll
        for (int cp = 0; cp < 4; ++cp) {
            int c0 = cg + cp * 2;
            float w0 = inv * nw[g * 32 + c0];
            float b0 = nb[g * 32 + c0] - mean * w0;
            float w1 = inv * nw[g * 32 + c0 + 1];
            float b1 = nb[g * 32 + c0 + 1] - mean * w1;
            float4 v0 = *(const float4*)&xs[(size_t)c0 * 1024 + n];
            float4 v1 = *(const float4*)&xs[(size_t)(c0 + 1) * 1024 + n];
            pk[0][cp] = cvt2(v0.x * w0 + b0, v1.x * w1 + b1);
            pk[1][cp] = cvt2(v0.y * w0 + b0, v1.y * w1 + b1);
            pk[2][cp] = cvt2(v0.z * w0 + b0, v1.z * w1 + b1);
            pk[3][cp] = cvt2(v0.w * w0 + b0, v1.w * w1 + b1);
        }
#pragma unroll
        for (int k = 0; k < 4; ++k) {
            uint4 u; u.x = pk[k][0]; u.y = pk[k][1]; u.z = pk[k][2]; u.w = pk[k][3];
            *(uint4*)&xt[((size_t)(b * 1024 + n + k)) * 256 + g * 32 + cg] = u;
        }
    } else {
        int idx = ((blk - 128) * 1024 + t) * 4;
        if (idx < 196608) {
            int row = idx >> 8;
            float sc = (row < 256) ? QSC : 1.f;
            float4 v = *(const float4*)&qkvw[idx];
            uint2 u; u.x = cvt2(v.x * sc, v.y * sc); u.y = cvt2(v.z * sc, v.w * sc);
            *(uint2*)&wqb[idx] = u;
        } else {
            int j = idx - 196608;
            float4 v = *(const float4*)&pw[j];
            uint2 u; u.x = cvt2(v.x, v.y); u.y = cvt2(v.z, v.w);
            *(uint2*)&pwb[j] = u;
        }
    }
}

// ---------------------------------------------------------------------------
// K3: qkv GEMM (unchanged, proven): BK=64 async dbuf, 1 barrier/iter.
// 128x128 tile, 4 waves. cy 0..3 -> qkT transposed; cy 4..5 -> vbuf natural.
// ---------------------------------------------------------------------------
__global__ __launch_bounds__(256, 2) void qkv_gemm_k(
    const ushort* __restrict__ wq, const ushort* __restrict__ xt,
    const float* __restrict__ wb, ushort* __restrict__ qkT,
    ushort* __restrict__ vbuf) {
    int b = blockIdx.z, cy = blockIdx.y, sx = blockIdx.x;
    __shared__ ushort SB[2][2][128 * 64];
    int t = threadIdx.x, lane = t & 63, w = t >> 6;
    int quad = lane >> 4, l15 = lane & 15;
    int wm = w >> 1, wn = w & 1;
    const ushort* wrow = wq + (size_t)cy * 128 * 256;
    const ushort* xrow = xt + ((size_t)b * 1024 + sx * 128) * 256;
    bool tpath = (cy < 4);
    int r0 = t >> 3;
    int cs = (t & 7) ^ (r0 & 7);
    int dst = t * 8;
#pragma unroll
    for (int ps = 0; ps < 4; ++ps) {
        int r = r0 + ps * 32;
        gl_lds16(&wrow[(size_t)r * 256 + cs * 8], &SB[0][0][ps * 2048 + dst]);
        gl_lds16(&xrow[(size_t)r * 256 + cs * 8], &SB[0][1][ps * 2048 + dst]);
    }
    __syncthreads();
    int s0 = quad ^ (l15 & 7);
    f32x4 acc[4][4] = {};
    int cur = 0;
    for (int ki = 0; ki < 4; ++ki) {
        if (ki < 3) {
            int k0 = (ki + 1) * 64, nx = cur ^ 1;
#pragma unroll
            for (int ps = 0; ps < 4; ++ps) {
                int r = r0 + ps * 32;
                gl_lds16(&wrow[(size_t)r * 256 + k0 + cs * 8], &SB[nx][0][ps * 2048 + dst]);
                gl_lds16(&xrow[(size_t)r * 256 + k0 + cs * 8], &SB[nx][1][ps * 2048 + dst]);
            }
        }
        const ushort* Wc = SB[cur][0];
        const ushort* Xc = SB[cur][1];
        const ushort* Am = tpath ? Xc : Wc;
        const ushort* Bn = tpath ? Wc : Xc;
#pragma unroll
        for (int kk = 0; kk < 2; ++kk) {
            int sl = s0 ^ (kk * 4);
            bf16x8 fa[4], fb[4];
#pragma unroll
            for (int mi = 0; mi < 4; ++mi)
                fa[mi] = *(const bf16x8*)&Am[(wm * 64 + mi * 16 + l15) * 64 + sl * 8];
#pragma unroll
            for (int ni = 0; ni < 4; ++ni)
                fb[ni] = *(const bf16x8*)&Bn[(wn * 64 + ni * 16 + l15) * 64 + sl * 8];
#pragma unroll
            for (int mi = 0; mi < 4; ++mi)
#pragma unroll
                for (int ni = 0; ni < 4; ++ni)
                    acc[mi][ni] = __builtin_amdgcn_mfma_f32_16x16x32_bf16(
                        fa[mi], fb[ni], acc[mi][ni], 0, 0, 0);
        }
        __syncthreads();
        cur ^= 1;
    }
    __syncthreads();
    ushort* Tw = ((ushort*)SB) + w * (64 * 72);
    float bsc = (tpath && cy < 2) ? QSC : 1.f;
    if (tpath) {
#pragma unroll
        for (int ni = 0; ni < 4; ++ni) {
            float bias = wb[cy * 128 + wn * 64 + ni * 16 + l15] * bsc;
#pragma unroll
            for (int mi = 0; mi < 4; ++mi)
#pragma unroll
                for (int rr = 0; rr < 4; ++rr)
                    Tw[(mi * 16 + quad * 4 + rr) * 72 + ni * 16 + l15] =
                        f2bf_fast(acc[mi][ni][rr] + bias);
        }
    } else {
#pragma unroll
        for (int mi = 0; mi < 4; ++mi)
#pragma unroll
            for (int rr = 0; rr < 4; ++rr) {
                float bias = wb[cy * 128 + wm * 64 + mi * 16 + quad * 4 + rr];
#pragma unroll
                for (int ni = 0; ni < 4; ++ni)
                    Tw[(mi * 16 + quad * 4 + rr) * 72 + ni * 16 + l15] =
                        f2bf_fast(acc[mi][ni][rr] + bias);
            }
    }
    __asm__ __volatile__("" ::: "memory");
    int row8 = lane >> 3, ch = lane & 7;
#pragma unroll
    for (int p = 0; p < 8; ++p) {
        int row = p * 8 + row8;
        uint4 u = *(const uint4*)&Tw[row * 72 + ch * 8];
        if (tpath) {
            int sp = sx * 128 + wm * 64 + row;
            *(uint4*)&qkT[((size_t)b * 1024 + sp) * 512 + cy * 128 + wn * 64 + ch * 8] = u;
        } else {
            int chanloc = (cy - 4) * 128 + wm * 64 + row;
            *(uint4*)&vbuf[((size_t)b * 256 + chanloc) * 1024 + sx * 128 + wn * 64 + ch * 8] = u;
        }
    }
}

// ---------------------------------------------------------------------------
// K4: flash attention (unchanged from R6): 4 waves x 32 i-rows, full
// j-range per wave, j-tile 128 (64KB LDS dbuf, 8 barriers), 2 blocks/CU.
// Swapped QK (A=K, B=Q): in-register softmax; P->bf16 via cvt_pk +
// permlane32_swap; O computed transposed.
// ---------------------------------------------------------------------------
__global__ __launch_bounds__(256, 2) void attn_k(
    const ushort* __restrict__ qkT, const ushort* __restrict__ vbuf,
    ushort* __restrict__ ot) {
    int bh = blockIdx.x;
    int i0 = blockIdx.y * 128;
    int b = bh >> 2, h = bh & 3;
    const ushort* qTb = qkT + (size_t)b * 1024 * 512 + h * 64;
    const ushort* kTb = qTb + 256;
    const ushort* vb  = vbuf + ((size_t)(b * 256 + h * 64)) * 1024;
    __shared__ ushort SM[32768];          // Ks[2][8192] | Vs[2][8192] (64KB)
    ushort* Ks0 = SM;
    ushort* Vs0 = SM + 16384;
    int t = threadIdx.x, lane = t & 63, wv = t >> 6;
    int l31 = lane & 31, hf = lane >> 5;
    int rk = t >> 3, pk = t & 7;          // K staging: 32 rows x 8 chunks
    int rv = t >> 4, pv = t & 15;         // V staging: 16 rows x 16 chunks
    // stage j-tile 0: K 128x64, V 64x128
#pragma unroll
    for (int seg = 0; seg < 4; ++seg) {
        int krow = seg * 32 + rk;
        int kc = pk ^ (krow & 7);
        gl_lds16(&kTb[(size_t)krow * 512 + kc * 8], &Ks0[seg * 2048 + t * 8]);
        int vrow = seg * 16 + rv;
        int vc = pv ^ (vrow & 7);
        gl_lds16(&vb[(size_t)vrow * 1024 + vc * 8], &Vs0[seg * 2048 + t * 8]);
    }
    // Q frags direct from global: B-frag col=i=l31, k = ks*16 + hf*8 + e
    bf16x8 qf[4];
#pragma unroll
    for (int ks = 0; ks < 4; ++ks)
        qf[ks] = *(const bf16x8*)
            &qTb[(size_t)(i0 + wv * 32 + l31) * 512 + ks * 16 + hf * 8];
    __syncthreads();
    f32x16 oT0 = {}, oT1 = {};   // O^T[d][i], d-halves
    float lsum = 0.f;
    int cur = 0;
    for (int j0 = 0; j0 < 1024; j0 += 128) {
        ushort* Kc = Ks0 + cur * 8192;
        ushort* Vc = Vs0 + cur * 8192;
        if (j0 < 896) {
            int nx = cur ^ 1;
            ushort* Kn = Ks0 + nx * 8192;
            ushort* Vn = Vs0 + nx * 8192;
#pragma unroll
            for (int seg = 0; seg < 4; ++seg) {
                int krow = seg * 32 + rk;
                int kc = pk ^ (krow & 7);
                gl_lds16(&kTb[(size_t)(j0 + 128 + krow) * 512 + kc * 8], &Kn[seg * 2048 + t * 8]);
                int vrow = seg * 16 + rv;
                int vc = pv ^ (vrow & 7);
                gl_lds16(&vb[(size_t)vrow * 1024 + j0 + 128 + vc * 8], &Vn[seg * 2048 + t * 8]);
            }
        }
#pragma unroll
        for (int jb = 0; jb < 4; ++jb) {
            // QK^T: S[j][i], rows j = j0 + jb*32 + (r&3)+8*(r>>2)+4*hf, col i = l31
            f32x16 s = {};
            __builtin_amdgcn_s_setprio(1);
#pragma unroll
            for (int ks = 0; ks < 4; ++ks) {
                int row = jb * 32 + l31;
                int c = (2 * ks + hf) ^ (row & 7);
                bf16x8 ak = *(const bf16x8*)&Kc[row * 64 + c * 8];
                s = __builtin_amdgcn_mfma_f32_32x32x16_bf16(ak, qf[ks], s, 0, 0, 0);
            }
            __builtin_amdgcn_s_setprio(0);
            // exp + pack (fused) + row-sum accumulate
            uint w0[4], w1[4];
#pragma unroll
            for (int q = 0; q < 4; ++q) {
                float e0 = EXP2F(s[q * 4 + 0]), e1 = EXP2F(s[q * 4 + 1]);
                float e2 = EXP2F(s[q * 4 + 2]), e3 = EXP2F(s[q * 4 + 3]);
                lsum += (e0 + e1) + (e2 + e3);
                w0[q] = cvt2(e0, e1);
                w1[q] = cvt2(e2, e3);
            }
            bf16x8 pf[2];
#pragma unroll
            for (int s2 = 0; s2 < 2; ++s2) {
                uint2v ra = plswap(w0[2 * s2], w0[2 * s2 + 1]);
                uint2v rb = plswap(w1[2 * s2], w1[2 * s2 + 1]);
                uint4 u; u.x = ra.x; u.y = rb.x; u.z = ra.y; u.w = rb.y;
                bf16x8 v; __builtin_memcpy(&v, &u, 16);
                pf[s2] = v;
            }
            // PV: O^T[d][i] += V^T[d][j-slot] * P[j-slot][i]
            __builtin_amdgcn_s_setprio(1);
#pragma unroll
            for (int s2 = 0; s2 < 2; ++s2) {
#pragma unroll
                for (int db = 0; db < 2; ++db) {
                    int row = db * 32 + l31;
                    int c = (jb * 4 + s2 * 2 + hf) ^ (row & 7);
                    bf16x8 av = *(const bf16x8*)&Vc[row * 128 + c * 8];
                    if (db == 0)
                        oT0 = __builtin_amdgcn_mfma_f32_32x32x16_bf16(av, pf[s2], oT0, 0, 0, 0);
                    else
                        oT1 = __builtin_amdgcn_mfma_f32_32x32x16_bf16(av, pf[s2], oT1, 0, 0, 0);
                }
            }
            __builtin_amdgcn_s_setprio(0);
        }
        __syncthreads();
        cur ^= 1;
    }
    lsum += __shfl_xor(lsum, 32);
    float linv = 1.f / lsum;
    // epilogue: per-wave LDS transpose (stride-33 dwords), then coalesced store
    uint* Os = (uint*)SM + wv * (32 * 33);
#pragma unroll
    for (int db = 0; db < 2; ++db) {
        f32x16 ov = (db == 0) ? oT0 : oT1;
#pragma unroll
        for (int q = 0; q < 4; ++q) {
            uint wa  = cvt2(ov[q * 4 + 0] * linv, ov[q * 4 + 1] * linv);
            uint wb2 = cvt2(ov[q * 4 + 2] * linv, ov[q * 4 + 3] * linv);
            int base = l31 * 33 + db * 16 + q * 4 + 2 * hf;
            Os[base]     = wa;
            Os[base + 1] = wb2;
        }
    }
    __asm__ __volatile__("" ::: "memory");
#pragma unroll
    for (int rr = 0; rr < 4; ++rr) {
        int irow = (lane >> 3) + rr * 8;
        const uint* rp = &Os[irow * 33 + (lane & 7) * 4];
        uint4 u; u.x = rp[0]; u.y = rp[1]; u.z = rp[2]; u.w = rp[3];
        *(uint4*)&ot[((size_t)b * 1024 + i0 + wv * 32 + irow) * 256 + h * 64 + (lane & 7) * 8] = u;
    }
}

// ---------------------------------------------------------------------------
// K5: proj GEMM + bias + residual. Round-7: nontemporal x-load / out-store
// (both are 64MB streaming, read/written exactly once -> keep L2 for ot,
// which cy-paired blocks re-read). Structure otherwise unchanged.
// ---------------------------------------------------------------------------
__global__ __launch_bounds__(256, 3) void proj_k(
    const ushort* __restrict__ pwb, const ushort* __restrict__ ot,
    const float* __restrict__ pb, const float* __restrict__ x,
    float* __restrict__ out) {
    int b = blockIdx.z, cy = blockIdx.y, sx = blockIdx.x;
    __shared__ ushort SB[2][12288];  // [buf][ W 128*64 | X 64*64 ] = 48KB
    int t = threadIdx.x, lane = t & 63, w = t >> 6;
    int quad = lane >> 4, l15 = lane & 15;
    int wm = w >> 1, wn = w & 1;
    const ushort* wrow = pwb + (size_t)cy * 128 * 256;
    const ushort* xrow = ot + ((size_t)b * 1024 + sx * 64) * 256;
    int r0 = t >> 3;
    int cs = (t & 7) ^ (r0 & 7);
    int dst = t * 8;
#pragma unroll
    for (int ps = 0; ps < 4; ++ps)
        gl_lds16(&wrow[(size_t)(r0 + ps * 32) * 256 + cs * 8], &SB[0][ps * 2048 + dst]);
#pragma unroll
    for (int ps = 0; ps < 2; ++ps)
        gl_lds16(&xrow[(size_t)(r0 + ps * 32) * 256 + cs * 8], &SB[0][8192 + ps * 2048 + dst]);
    __syncthreads();
    int p0 = quad ^ (l15 & 7);
    f32x4 acc[4][2] = {};
    int cur = 0;
    for (int ki = 0; ki < 4; ++ki) {
        if (ki < 3) {
            int k0 = (ki + 1) * 64, nx = cur ^ 1;
#pragma unroll
            for (int ps = 0; ps < 4; ++ps)
                gl_lds16(&wrow[(size_t)(r0 + ps * 32) * 256 + k0 + cs * 8], &SB[nx][ps * 2048 + dst]);
#pragma unroll
            for (int ps = 0; ps < 2; ++ps)
                gl_lds16(&xrow[(size_t)(r0 + ps * 32) * 256 + k0 + cs * 8], &SB[nx][8192 + ps * 2048 + dst]);
        }
        const ushort* Wc = &SB[cur][0];
        const ushort* Xc = &SB[cur][8192];
#pragma unroll
        for (int kk = 0; kk < 2; ++kk) {
            int sl = p0 ^ (kk * 4);
            bf16x8 fa[4], fb[2];
#pragma unroll
            for (int mi = 0; mi < 4; ++mi)
                fa[mi] = *(const bf16x8*)&Wc[(wm * 64 + mi * 16 + l15) * 64 + sl * 8];
#pragma unroll
            for (int ni = 0; ni < 2; ++ni)
                fb[ni] = *(const bf16x8*)&Xc[(wn * 32 + ni * 16 + l15) * 64 + sl * 8];
#pragma unroll
            for (int mi = 0; mi < 4; ++mi)
#pragma unroll
                for (int ni = 0; ni < 2; ++ni)
                    acc[mi][ni] = __builtin_amdgcn_mfma_f32_16x16x32_bf16(
                        fa[mi], fb[ni], acc[mi][ni], 0, 0, 0);
        }
        __syncthreads();
        cur ^= 1;
    }
#pragma unroll
    for (int mi = 0; mi < 4; ++mi)
#pragma unroll
        for (int rr = 0; rr < 4; ++rr) {
            int chan = cy * 128 + wm * 64 + mi * 16 + quad * 4 + rr;
            float bias = pb[chan];
#pragma unroll
            for (int ni = 0; ni < 2; ++ni) {
                int sp = sx * 64 + wn * 32 + ni * 16 + l15;
                size_t o = ((size_t)(b * 256 + chan)) * 1024 + sp;
                float xr = __builtin_nontemporal_load(&x[o]);
                __builtin_nontemporal_store(acc[mi][ni][rr] + bias + xr, &out[o]);
            }
        }
}

// ---------------------------------------------------------------------------
extern "C" void kernel_launch(void* const* d_in, const int* in_sizes, int n_in,
                              void* d_out, int out_size, void* d_ws, size_t ws_size,
                              hipStream_t stream) {
    const float* x    = (const float*)d_in[0];
    const float* nw   = (const float*)d_in[1];
    const float* nb   = (const float*)d_in[2];
    const float* qkvw = (const float*)d_in[3];
    const float* qkvb = (const float*)d_in[4];
    const float* pw   = (const float*)d_in[5];
    const float* pb   = (const float*)d_in[6];
    float* out = (float*)d_out;

    // Workspace (~34 MB): xt | wqb | pwb | qkT | vbuf; ot aliases xt.
    ushort* base = (ushort*)d_ws;
    ushort* xt   = base;                          // 16*1024*256
    ushort* wqb  = xt + (size_t)16 * 1024 * 256;  // 768*256
    ushort* pwb  = wqb + 768 * 256;               // 256*256
    ushort* qkT  = pwb + 256 * 256;               // 16*1024*512
    ushort* vbuf = qkT + (size_t)16 * 1024 * 512; // 16*256*1024
    ushort* ot   = xt;                            // reuse

    norm_k<<<dim3(192), dim3(1024), 0, stream>>>(x, nw, nb, qkvw, pw, xt, wqb, pwb);
    qkv_gemm_k<<<dim3(8, 6, Bc), dim3(256), 0, stream>>>(wqb, xt, qkvb, qkT, vbuf);
    attn_k<<<dim3(64, 8), dim3(256), 0, stream>>>(qkT, vbuf, ot);
    proj_k<<<dim3(16, 2, Bc), dim3(256), 0, stream>>>(pwb, ot, pb, x, out);
}

// Round 8
// 125.076 us; speedup vs baseline: 1.0416x; 1.0015x over previous
//
#include <hip/hip_runtime.h>
#include <math.h>

typedef unsigned short ushort;
typedef unsigned int uint;
typedef __attribute__((ext_vector_type(8))) short bf16x8;
typedef __attribute__((ext_vector_type(4))) float f32x4;
typedef __attribute__((ext_vector_type(16))) float f32x16;
typedef __attribute__((ext_vector_type(2))) unsigned uint2v;

constexpr int Bc  = 16;
constexpr float EPSc = 1e-5f;
constexpr float QSC  = 0.18033688f;  // 0.125 * log2(e): softmax exp -> exp2

// v_cvt_pk_bf16_f32: one instr per bf16 pair (no builtin on gfx950)
__device__ __forceinline__ uint cvt2(float a, float b) {
    uint r;
    asm("v_cvt_pk_bf16_f32 %0, %1, %2" : "=v"(r) : "v"(a), "v"(b));
    return r;
}
__device__ __forceinline__ ushort f2bf_fast(float f) {
    uint r;
    asm("v_cvt_pk_bf16_f32 %0, %1, %2" : "=v"(r) : "v"(f), "v"(f));
    return (ushort)r;
}
// permlane32_swap: r.x = [a.lanes0-31 | b.lanes0-31], r.y = [a.lanes32-63 | b.lanes32-63]
__device__ __forceinline__ uint2v plswap(uint a, uint b) {
#if __has_builtin(__builtin_amdgcn_permlane32_swap)
    return __builtin_amdgcn_permlane32_swap(a, b, false, false);
#else
    asm volatile("v_permlane32_swap_b32 %0, %1" : "+v"(a), "+v"(b));
    uint2v r; r.x = a; r.y = b; return r;
#endif
}
#if __has_builtin(__builtin_amdgcn_exp2f)
#define EXP2F(x) __builtin_amdgcn_exp2f(x)
#else
#define EXP2F(x) __expf((x) * 0.69314718f)
#endif
__device__ __forceinline__ void gl_lds16(const ushort* g, ushort* l) {
    __builtin_amdgcn_global_load_lds(
        (const __attribute__((address_space(1))) void*)g,
        (__attribute__((address_space(3))) void*)l, 16, 0, 0);
}

// ---------------------------------------------------------------------------
// K1: fused GroupNorm (two-pass, proven; pass-2 vectorized). Blocks
// 0..127: one (b,g) slice each. Blocks 128..191: weight cvt.
// ---------------------------------------------------------------------------
__global__ __launch_bounds__(1024, 4) void norm_k(
    const float* __restrict__ x, const float* __restrict__ nw,
    const float* __restrict__ nb, const float* __restrict__ qkvw,
    const float* __restrict__ pw, ushort* __restrict__ xt,
    ushort* __restrict__ wqb, ushort* __restrict__ pwb) {
    int blk = blockIdx.x;
    int t = threadIdx.x;
    if (blk < 128) {
        int b = blk >> 3, g = blk & 7;
        const float* xs = x + ((size_t)(b * 8 + g)) * 32768;
        const float4* p4 = (const float4*)xs;
        float s = 0.f, s2 = 0.f;
#pragma unroll
        for (int i = 0; i < 8; ++i) {
            float4 v = p4[t + i * 1024];
            s += (v.x + v.y) + (v.z + v.w);
            s2 += (v.x * v.x + v.y * v.y) + (v.z * v.z + v.w * v.w);
        }
#pragma unroll
        for (int off = 1; off < 64; off <<= 1) {
            s += __shfl_xor(s, off);
            s2 += __shfl_xor(s2, off);
        }
        __shared__ float rs[16], rq[16], bc[2];
        int wv = t >> 6, lane = t & 63;
        if (lane == 0) { rs[wv] = s; rq[wv] = s2; }
        __syncthreads();
        if (t == 0) {
            float ts = 0.f, tq = 0.f;
#pragma unroll
            for (int i = 0; i < 16; ++i) { ts += rs[i]; tq += rq[i]; }
            float mean = ts * (1.f / 32768.f);
            float var  = tq * (1.f / 32768.f) - mean * mean;
            bc[0] = mean; bc[1] = rsqrtf(var + EPSc);
        }
        __syncthreads();
        float mean = bc[0], inv = bc[1];
        int n = (t & 255) * 4;
        int cg = (t >> 8) * 8;
        uint pk[4][4];   // [k in n][c-pair]
#pragma unroll
        for (int cp = 0; cp < 4; ++cp) {
            int c0 = cg + cp * 2;
            float w0 = inv * nw[g * 32 + c0];
            float b0 = nb[g * 32 + c0] - mean * w0;
            float w1 = inv * nw[g * 32 + c0 + 1];
            float b1 = nb[g * 32 + c0 + 1] - mean * w1;
            float4 v0 = *(const float4*)&xs[(size_t)c0 * 1024 + n];
            float4 v1 = *(const float4*)&xs[(size_t)(c0 + 1) * 1024 + n];
            pk[0][cp] = cvt2(v0.x * w0 + b0, v1.x * w1 + b1);
            pk[1][cp] = cvt2(v0.y * w0 + b0, v1.y * w1 + b1);
            pk[2][cp] = cvt2(v0.z * w0 + b0, v1.z * w1 + b1);
            pk[3][cp] = cvt2(v0.w * w0 + b0, v1.w * w1 + b1);
        }
#pragma unroll
        for (int k = 0; k < 4; ++k) {
            uint4 u; u.x = pk[k][0]; u.y = pk[k][1]; u.z = pk[k][2]; u.w = pk[k][3];
            *(uint4*)&xt[((size_t)(b * 1024 + n + k)) * 256 + g * 32 + cg] = u;
        }
    } else {
        int idx = ((blk - 128) * 1024 + t) * 4;
        if (idx < 196608) {
            int row = idx >> 8;
            float sc = (row < 256) ? QSC : 1.f;
            float4 v = *(const float4*)&qkvw[idx];
            uint2 u; u.x = cvt2(v.x * sc, v.y * sc); u.y = cvt2(v.z * sc, v.w * sc);
            *(uint2*)&wqb[idx] = u;
        } else {
            int j = idx - 196608;
            float4 v = *(const float4*)&pw[j];
            uint2 u; u.x = cvt2(v.x, v.y); u.y = cvt2(v.z, v.w);
            *(uint2*)&pwb[j] = u;
        }
    }
}

// ---------------------------------------------------------------------------
// K3: qkv GEMM, round-8: BK=32 dbuf -> 36KB LDS -> 3 blocks/CU; grid 768
// = 3x256 EXACTLY -> one dispatch round, no tail (was 1.5 rounds @ 2/CU).
// LDS tile packs row-PAIRS into 128B LDS rows (row r -> LDS row r>>1,
// chunk (r&1)*4 + k-chunk) so frag reads keep the full-32-bank spread;
// source-address XOR swizzle cc0 = cc ^ (R&7) (both-sides rule #21).
// cy 0..3 -> qkT transposed; cy 4..5 -> vbuf natural.
// ---------------------------------------------------------------------------
__global__ __launch_bounds__(256, 3) void qkv_gemm_k(
    const ushort* __restrict__ wq, const ushort* __restrict__ xt,
    const float* __restrict__ wb, ushort* __restrict__ qkT,
    ushort* __restrict__ vbuf) {
    int b = blockIdx.z, cy = blockIdx.y, sx = blockIdx.x;
    __shared__ ushort SM[18432];  // 36KB: W0|X0|W1|X1 (4x8KB) ; epilogue 4x4608
    int t = threadIdx.x, lane = t & 63, w = t >> 6;
    int quad = lane >> 4, l15 = lane & 15;
    int wm = w >> 1, wn = w & 1;
    const ushort* wrow = wq + (size_t)cy * 128 * 256;
    const ushort* xrow = xt + ((size_t)b * 1024 + sx * 128) * 256;
    bool tpath = (cy < 4);
    int R0 = t >> 3, cc_s = t & 7;
    // stage one 128x32 tile (512 x 16B chunks; 2 chunks/thread)
    auto stage = [&](const ushort* mat, ushort* dstbuf, int k0) {
#pragma unroll
        for (int ps = 0; ps < 2; ++ps) {
            int R = R0 + ps * 32;
            int cc0 = cc_s ^ (R & 7);
            int gr = 2 * R + (cc0 >> 2);
            int gc = (cc0 & 3) * 8;
            gl_lds16(&mat[(size_t)gr * 256 + k0 + gc], &dstbuf[(ps * 256 + t) * 8]);
        }
    };
    stage(wrow, SM, 0);
    stage(xrow, SM + 4096, 0);
    __syncthreads();
    f32x4 acc[4][4] = {};
    int cur = 0;
    for (int ki = 0; ki < 8; ++ki) {
        if (ki < 7) {
            int k0 = (ki + 1) * 32, nx = cur ^ 1;
            stage(wrow, SM + nx * 8192, k0);
            stage(xrow, SM + nx * 8192 + 4096, k0);
        }
        const ushort* Wc = SM + cur * 8192;
        const ushort* Xc = SM + cur * 8192 + 4096;
        const ushort* Am = tpath ? Xc : Wc;
        const ushort* Bn = tpath ? Wc : Xc;
        bf16x8 fa[4], fb[4];
#pragma unroll
        for (int mi = 0; mi < 4; ++mi) {
            int r = wm * 64 + mi * 16 + l15;
            int R = r >> 1;
            int cc = ((r & 1) * 4 + quad) ^ (R & 7);
            fa[mi] = *(const bf16x8*)&Am[R * 64 + cc * 8];
        }
#pragma unroll
        for (int ni = 0; ni < 4; ++ni) {
            int r = wn * 64 + ni * 16 + l15;
            int R = r >> 1;
            int cc = ((r & 1) * 4 + quad) ^ (R & 7);
            fb[ni] = *(const bf16x8*)&Bn[R * 64 + cc * 8];
        }
#pragma unroll
        for (int mi = 0; mi < 4; ++mi)
#pragma unroll
            for (int ni = 0; ni < 4; ++ni)
                acc[mi][ni] = __builtin_amdgcn_mfma_f32_16x16x32_bf16(
                    fa[mi], fb[ni], acc[mi][ni], 0, 0, 0);
        __syncthreads();
        cur ^= 1;
    }
    __syncthreads();
    ushort* Tw = SM + w * 4608;   // 64 x 72 per wave
    float bsc = (tpath && cy < 2) ? QSC : 1.f;
    if (tpath) {
#pragma unroll
        for (int ni = 0; ni < 4; ++ni) {
            float bias = wb[cy * 128 + wn * 64 + ni * 16 + l15] * bsc;
#pragma unroll
            for (int mi = 0; mi < 4; ++mi)
#pragma unroll
                for (int rr = 0; rr < 4; ++rr)
                    Tw[(mi * 16 + quad * 4 + rr) * 72 + ni * 16 + l15] =
                        f2bf_fast(acc[mi][ni][rr] + bias);
        }
    } else {
#pragma unroll
        for (int mi = 0; mi < 4; ++mi)
#pragma unroll
            for (int rr = 0; rr < 4; ++rr) {
                float bias = wb[cy * 128 + wm * 64 + mi * 16 + quad * 4 + rr];
#pragma unroll
                for (int ni = 0; ni < 4; ++ni)
                    Tw[(mi * 16 + quad * 4 + rr) * 72 + ni * 16 + l15] =
                        f2bf_fast(acc[mi][ni][rr] + bias);
            }
    }
    __asm__ __volatile__("" ::: "memory");
    int row8 = lane >> 3, ch = lane & 7;
#pragma unroll
    for (int p = 0; p < 8; ++p) {
        int row = p * 8 + row8;
        uint4 u = *(const uint4*)&Tw[row * 72 + ch * 8];
        if (tpath) {
            int sp = sx * 128 + wm * 64 + row;
            *(uint4*)&qkT[((size_t)b * 1024 + sp) * 512 + cy * 128 + wn * 64 + ch * 8] = u;
        } else {
            int chanloc = (cy - 4) * 128 + wm * 64 + row;
            *(uint4*)&vbuf[((size_t)b * 256 + chanloc) * 1024 + sx * 128 + wn * 64 + ch * 8] = u;
        }
    }
}

// ---------------------------------------------------------------------------
// K4: flash attention (unchanged from R7 best): 4 waves x 32 i-rows, full
// j-range per wave, j-tile 128 (64KB LDS dbuf), 2 blocks/CU. Swapped QK
// (A=K, B=Q): in-register softmax; P->bf16 via cvt_pk + permlane32_swap;
// O computed transposed.
// ---------------------------------------------------------------------------
__global__ __launch_bounds__(256, 2) void attn_k(
    const ushort* __restrict__ qkT, const ushort* __restrict__ vbuf,
    ushort* __restrict__ ot) {
    int bh = blockIdx.x;
    int i0 = blockIdx.y * 128;
    int b = bh >> 2, h = bh & 3;
    const ushort* qTb = qkT + (size_t)b * 1024 * 512 + h * 64;
    const ushort* kTb = qTb + 256;
    const ushort* vb  = vbuf + ((size_t)(b * 256 + h * 64)) * 1024;
    __shared__ ushort SM[32768];          // Ks[2][8192] | Vs[2][8192] (64KB)
    ushort* Ks0 = SM;
    ushort* Vs0 = SM + 16384;
    int t = threadIdx.x, lane = t & 63, wv = t >> 6;
    int l31 = lane & 31, hf = lane >> 5;
    int rk = t >> 3, pk = t & 7;          // K staging: 32 rows x 8 chunks
    int rv = t >> 4, pv = t & 15;         // V staging: 16 rows x 16 chunks
#pragma unroll
    for (int seg = 0; seg < 4; ++seg) {
        int krow = seg * 32 + rk;
        int kc = pk ^ (krow & 7);
        gl_lds16(&kTb[(size_t)krow * 512 + kc * 8], &Ks0[seg * 2048 + t * 8]);
        int vrow = seg * 16 + rv;
        int vc = pv ^ (vrow & 7);
        gl_lds16(&vb[(size_t)vrow * 1024 + vc * 8], &Vs0[seg * 2048 + t * 8]);
    }
    bf16x8 qf[4];
#pragma unroll
    for (int ks = 0; ks < 4; ++ks)
        qf[ks] = *(const bf16x8*)
            &qTb[(size_t)(i0 + wv * 32 + l31) * 512 + ks * 16 + hf * 8];
    __syncthreads();
    f32x16 oT0 = {}, oT1 = {};   // O^T[d][i], d-halves
    float lsum = 0.f;
    int cur = 0;
    for (int j0 = 0; j0 < 1024; j0 += 128) {
        ushort* Kc = Ks0 + cur * 8192;
        ushort* Vc = Vs0 + cur * 8192;
        if (j0 < 896) {
            int nx = cur ^ 1;
            ushort* Kn = Ks0 + nx * 8192;
            ushort* Vn = Vs0 + nx * 8192;
#pragma unroll
            for (int seg = 0; seg < 4; ++seg) {
                int krow = seg * 32 + rk;
                int kc = pk ^ (krow & 7);
                gl_lds16(&kTb[(size_t)(j0 + 128 + krow) * 512 + kc * 8], &Kn[seg * 2048 + t * 8]);
                int vrow = seg * 16 + rv;
                int vc = pv ^ (vrow & 7);
                gl_lds16(&vb[(size_t)vrow * 1024 + j0 + 128 + vc * 8], &Vn[seg * 2048 + t * 8]);
            }
        }
#pragma unroll
        for (int jb = 0; jb < 4; ++jb) {
            f32x16 s = {};
            __builtin_amdgcn_s_setprio(1);
#pragma unroll
            for (int ks = 0; ks < 4; ++ks) {
                int row = jb * 32 + l31;
                int c = (2 * ks + hf) ^ (row & 7);
                bf16x8 ak = *(const bf16x8*)&Kc[row * 64 + c * 8];
                s = __builtin_amdgcn_mfma_f32_32x32x16_bf16(ak, qf[ks], s, 0, 0, 0);
            }
            __builtin_amdgcn_s_setprio(0);
            uint w0[4], w1[4];
#pragma unroll
            for (int q = 0; q < 4; ++q) {
                float e0 = EXP2F(s[q * 4 + 0]), e1 = EXP2F(s[q * 4 + 1]);
                float e2 = EXP2F(s[q * 4 + 2]), e3 = EXP2F(s[q * 4 + 3]);
                lsum += (e0 + e1) + (e2 + e3);
                w0[q] = cvt2(e0, e1);
                w1[q] = cvt2(e2, e3);
            }
            bf16x8 pf[2];
#pragma unroll
            for (int s2 = 0; s2 < 2; ++s2) {
                uint2v ra = plswap(w0[2 * s2], w0[2 * s2 + 1]);
                uint2v rb = plswap(w1[2 * s2], w1[2 * s2 + 1]);
                uint4 u; u.x = ra.x; u.y = rb.x; u.z = ra.y; u.w = rb.y;
                bf16x8 v; __builtin_memcpy(&v, &u, 16);
                pf[s2] = v;
            }
            __builtin_amdgcn_s_setprio(1);
#pragma unroll
            for (int s2 = 0; s2 < 2; ++s2) {
#pragma unroll
                for (int db = 0; db < 2; ++db) {
                    int row = db * 32 + l31;
                    int c = (jb * 4 + s2 * 2 + hf) ^ (row & 7);
                    bf16x8 av = *(const bf16x8*)&Vc[row * 128 + c * 8];
                    if (db == 0)
                        oT0 = __builtin_amdgcn_mfma_f32_32x32x16_bf16(av, pf[s2], oT0, 0, 0, 0);
                    else
                        oT1 = __builtin_amdgcn_mfma_f32_32x32x16_bf16(av, pf[s2], oT1, 0, 0, 0);
                }
            }
            __builtin_amdgcn_s_setprio(0);
        }
        __syncthreads();
        cur ^= 1;
    }
    lsum += __shfl_xor(lsum, 32);
    float linv = 1.f / lsum;
    uint* Os = (uint*)SM + wv * (32 * 33);
#pragma unroll
    for (int db = 0; db < 2; ++db) {
        f32x16 ov = (db == 0) ? oT0 : oT1;
#pragma unroll
        for (int q = 0; q < 4; ++q) {
            uint wa  = cvt2(ov[q * 4 + 0] * linv, ov[q * 4 + 1] * linv);
            uint wb2 = cvt2(ov[q * 4 + 2] * linv, ov[q * 4 + 3] * linv);
            int base = l31 * 33 + db * 16 + q * 4 + 2 * hf;
            Os[base]     = wa;
            Os[base + 1] = wb2;
        }
    }
    __asm__ __volatile__("" ::: "memory");
#pragma unroll
    for (int rr = 0; rr < 4; ++rr) {
        int irow = (lane >> 3) + rr * 8;
        const uint* rp = &Os[irow * 33 + (lane & 7) * 4];
        uint4 u; u.x = rp[0]; u.y = rp[1]; u.z = rp[2]; u.w = rp[3];
        *(uint4*)&ot[((size_t)b * 1024 + i0 + wv * 32 + irow) * 256 + h * 64 + (lane & 7) * 8] = u;
    }
}

// ---------------------------------------------------------------------------
// K5: proj GEMM + bias + residual (unchanged from R7: nontemporal x/out).
// ---------------------------------------------------------------------------
__global__ __launch_bounds__(256, 3) void proj_k(
    const ushort* __restrict__ pwb, const ushort* __restrict__ ot,
    const float* __restrict__ pb, const float* __restrict__ x,
    float* __restrict__ out) {
    int b = blockIdx.z, cy = blockIdx.y, sx = blockIdx.x;
    __shared__ ushort SB[2][12288];  // [buf][ W 128*64 | X 64*64 ] = 48KB
    int t = threadIdx.x, lane = t & 63, w = t >> 6;
    int quad = lane >> 4, l15 = lane & 15;
    int wm = w >> 1, wn = w & 1;
    const ushort* wrow = pwb + (size_t)cy * 128 * 256;
    const ushort* xrow = ot + ((size_t)b * 1024 + sx * 64) * 256;
    int r0 = t >> 3;
    int cs = (t & 7) ^ (r0 & 7);
    int dst = t * 8;
#pragma unroll
    for (int ps = 0; ps < 4; ++ps)
        gl_lds16(&wrow[(size_t)(r0 + ps * 32) * 256 + cs * 8], &SB[0][ps * 2048 + dst]);
#pragma unroll
    for (int ps = 0; ps < 2; ++ps)
        gl_lds16(&xrow[(size_t)(r0 + ps * 32) * 256 + cs * 8], &SB[0][8192 + ps * 2048 + dst]);
    __syncthreads();
    int p0 = quad ^ (l15 & 7);
    f32x4 acc[4][2] = {};
    int cur = 0;
    for (int ki = 0; ki < 4; ++ki) {
        if (ki < 3) {
            int k0 = (ki + 1) * 64, nx = cur ^ 1;
#pragma unroll
            for (int ps = 0; ps < 4; ++ps)
                gl_lds16(&wrow[(size_t)(r0 + ps * 32) * 256 + k0 + cs * 8], &SB[nx][ps * 2048 + dst]);
#pragma unroll
            for (int ps = 0; ps < 2; ++ps)
                gl_lds16(&xrow[(size_t)(r0 + ps * 32) * 256 + k0 + cs * 8], &SB[nx][8192 + ps * 2048 + dst]);
        }
        const ushort* Wc = &SB[cur][0];
        const ushort* Xc = &SB[cur][8192];
#pragma unroll
        for (int kk = 0; kk < 2; ++kk) {
            int sl = p0 ^ (kk * 4);
            bf16x8 fa[4], fb[2];
#pragma unroll
            for (int mi = 0; mi < 4; ++mi)
                fa[mi] = *(const bf16x8*)&Wc[(wm * 64 + mi * 16 + l15) * 64 + sl * 8];
#pragma unroll
            for (int ni = 0; ni < 2; ++ni)
                fb[ni] = *(const bf16x8*)&Xc[(wn * 32 + ni * 16 + l15) * 64 + sl * 8];
#pragma unroll
            for (int mi = 0; mi < 4; ++mi)
#pragma unroll
                for (int ni = 0; ni < 2; ++ni)
                    acc[mi][ni] = __builtin_amdgcn_mfma_f32_16x16x32_bf16(
                        fa[mi], fb[ni], acc[mi][ni], 0, 0, 0);
        }
        __syncthreads();
        cur ^= 1;
    }
#pragma unroll
    for (int mi = 0; mi < 4; ++mi)
#pragma unroll
        for (int rr = 0; rr < 4; ++rr) {
            int chan = cy * 128 + wm * 64 + mi * 16 + quad * 4 + rr;
            float bias = pb[chan];
#pragma unroll
            for (int ni = 0; ni < 2; ++ni) {
                int sp = sx * 64 + wn * 32 + ni * 16 + l15;
                size_t o = ((size_t)(b * 256 + chan)) * 1024 + sp;
                float xr = __builtin_nontemporal_load(&x[o]);
                __builtin_nontemporal_store(acc[mi][ni][rr] + bias + xr, &out[o]);
            }
        }
}

// ---------------------------------------------------------------------------
extern "C" void kernel_launch(void* const* d_in, const int* in_sizes, int n_in,
                              void* d_out, int out_size, void* d_ws, size_t ws_size,
                              hipStream_t stream) {
    const float* x    = (const float*)d_in[0];
    const float* nw   = (const float*)d_in[1];
    const float* nb   = (const float*)d_in[2];
    const float* qkvw = (const float*)d_in[3];
    const float* qkvb = (const float*)d_in[4];
    const float* pw   = (const float*)d_in[5];
    const float* pb   = (const float*)d_in[6];
    float* out = (float*)d_out;

    // Workspace (~34 MB): xt | wqb | pwb | qkT | vbuf; ot aliases xt.
    ushort* base = (ushort*)d_ws;
    ushort* xt   = base;                          // 16*1024*256
    ushort* wqb  = xt + (size_t)16 * 1024 * 256;  // 768*256
    ushort* pwb  = wqb + 768 * 256;               // 256*256
    ushort* qkT  = pwb + 256 * 256;               // 16*1024*512
    ushort* vbuf = qkT + (size_t)16 * 1024 * 512; // 16*256*1024
    ushort* ot   = xt;                            // reuse

    norm_k<<<dim3(192), dim3(1024), 0, stream>>>(x, nw, nb, qkvw, pw, xt, wqb, pwb);
    qkv_gemm_k<<<dim3(8, 6, Bc), dim3(256), 0, stream>>>(wqb, xt, qkvb, qkT, vbuf);
    attn_k<<<dim3(64, 8), dim3(256), 0, stream>>>(qkT, vbuf, ot);
    proj_k<<<dim3(16, 2, Bc), dim3(256), 0, stream>>>(pwb, ot, pb, x, out);
}